// Round 5
// baseline (996.528 us; speedup 1.0000x reference)
//
#include <hip/hip_runtime.h>
#include <hip/hip_bf16.h>

// ---------------------------------------------------------------------------
// DEQ layer, MI355X round 9.
//  - NEW: gemm2+anderson fusion. gemm2 tile 16x256 (full output width, 128
//    blocks x 512 thr): each block computes complete F rows, then runs the
//    Anderson update for those rows reading F[t-1] from LDS. Saves per iter:
//    one launch + gap, the F re-read, and the standalone anderson's 14.7us
//    (round-8 back-computed). Solve in f32 (reference solves f32; keeps
//    VGPR<=128 for 2 blocks/CU).
//  - colsum folded into gram (64 extra blocks).
//  - gram 64x32 tiles / power chain 21 launches / gemm1 64x64: unchanged.
// ---------------------------------------------------------------------------

#define B_ROWS 2048
#define D_LAT  256
#define D_CTX  256
#define D_HID  1024
#define KCAT   512
#define SLOT   (B_ROWS * D_LAT)
#define NRING  7

typedef __bf16 bf16x8 __attribute__((ext_vector_type(8)));
typedef float f32x4 __attribute__((ext_vector_type(4)));
typedef unsigned short u16;

// ---------------- init: zc = [bf16(0)|bf16(ctx)], uA=1, vA=0, G=0 ----------
__global__ void init_kernel(const float* __restrict__ ctx,
                            __hip_bfloat16* __restrict__ zc,
                            float* __restrict__ vA, float* __restrict__ uA,
                            float* __restrict__ G1p, float* __restrict__ G2) {
  int i = blockIdx.x * 256 + threadIdx.x;
  if (i < B_ROWS * KCAT) {
    int b = i >> 9, c = i & 511;
    float v = (c < 256) ? 0.0f : ctx[b * 256 + (c - 256)];
    zc[i] = __float2bfloat16(v);
  }
  if (i < 512 * 512) G1p[i] = 0.0f;
  if (i < 256 * 256) G2[i] = 0.0f;
  if (i < KCAT) vA[i] = 0.0f;
  if (i < D_LAT) uA[i] = 1.0f;
}

// ---------------- Gram build + colsum, split-K x8, 64x32 tiles -------------
// blocks 0..1023:   G1' = W1^T W1 (mode A)
// blocks 1024..1279: G2 = W2 W2^T (mode B)
// blocks 1280..1343: colsum partials vA += W1^T ones (mode C)
__global__ __launch_bounds__(256) void gram_kernel(
    const float* __restrict__ W1, const float* __restrict__ W2,
    float* __restrict__ G1p, float* __restrict__ G2,
    float* __restrict__ vA) {
  __shared__ float As[32][66];
  __shared__ float Bs[32][34];
  const int tid = threadIdx.x;
  const int tx = tid & 15, ty = tid >> 4;

  int b = blockIdx.x;
  if (b >= 1280) {  // mode C: colsum
    int cb = b - 1280;
    for (int c = tid; c < KCAT; c += 256) {
      float s = 0.f;
#pragma unroll
      for (int r = 0; r < 16; r++) s += W1[(size_t)(16 * cb + r) * KCAT + c];
      atomicAdd(&vA[c], s);
    }
    return;
  }

  const float* X; float* G; int N, ti, tj, k0base; bool modeA;
  if (b < 1024) {
    modeA = true; X = W1; G = G1p; N = 512;
    int s = b >> 7, t = b & 127;
    ti = t >> 4; tj = t & 15; k0base = s * 128;
  } else {
    modeA = false; b -= 1024; X = W2; G = G2; N = 256;
    int s = b >> 5, t = b & 31;
    ti = t >> 3; tj = t & 7; k0base = s * 128;
  }

  float acc[4][2] = {};
  for (int k0 = k0base; k0 < k0base + 128; k0 += 32) {
    if (modeA) {
      for (int idx = tid; idx < 2048; idx += 256) {
        int r = idx & 63, c = idx >> 6;
        As[c][r] = X[(size_t)(k0 + c) * 512 + ti * 64 + r];
      }
      for (int idx = tid; idx < 1024; idx += 256) {
        int r = idx & 31, c = idx >> 5;
        Bs[c][r] = X[(size_t)(k0 + c) * 512 + tj * 32 + r];
      }
    } else {
      for (int idx = tid; idx < 2048; idx += 256) {
        int c = idx & 31, r = idx >> 5;
        As[c][r] = X[(size_t)(ti * 64 + r) * 1024 + k0 + c];
      }
      for (int idx = tid; idx < 1024; idx += 256) {
        int c = idx & 31, r = idx >> 5;
        Bs[c][r] = X[(size_t)(tj * 32 + r) * 1024 + k0 + c];
      }
    }
    __syncthreads();
#pragma unroll
    for (int kk = 0; kk < 32; kk++) {
      const float2* ap = (const float2*)&As[kk][ty * 4];
      float2 a0 = ap[0], a1 = ap[1];
      float2 b0 = *(const float2*)&Bs[kk][tx * 2];
      float a[4] = {a0.x, a0.y, a1.x, a1.y};
      float bb[2] = {b0.x, b0.y};
#pragma unroll
      for (int i = 0; i < 4; i++)
#pragma unroll
        for (int j = 0; j < 2; j++) acc[i][j] += a[i] * bb[j];
    }
    __syncthreads();
  }
#pragma unroll
  for (int i = 0; i < 4; i++)
#pragma unroll
    for (int j = 0; j < 2; j++)
      atomicAdd(&G[(size_t)(ti * 64 + ty * 4 + i) * N + tj * 32 + tx * 2 + j],
                acc[i][j]);
}

// ---------------- joint power matvec: out = 0.25 * G in --------------------
__global__ __launch_bounds__(256) void pmv_kernel(
    const float* __restrict__ G1p, const float* __restrict__ G2,
    const float* __restrict__ vi, float* __restrict__ vo,
    const float* __restrict__ ui, float* __restrict__ uo, int g1_active) {
  int gw = blockIdx.x * 4 + (threadIdx.x >> 6);
  int lane = threadIdx.x & 63;
  const float* G; const float* in; float* out; int n, r;
  if (gw < 512) {
    if (!g1_active) return;
    G = G1p; in = vi; out = vo; n = 512; r = gw;
  } else {
    G = G2; in = ui; out = uo; n = 256; r = gw - 512;
  }
  const float4* Gr = (const float4*)(G + (size_t)r * n);
  const float4* uv = (const float4*)in;
  float acc = 0.f;
  for (int c = lane; c < (n >> 2); c += 64) {
    float4 g = Gr[c], u = uv[c];
    acc += g.x * u.x + g.y * u.y + g.z * u.z + g.w * u.w;
  }
  for (int off = 32; off; off >>= 1) acc += __shfl_down(acc, off, 64);
  if (lane == 0) out[r] = 0.25f * acc;
}

// ---------------- sigma ----------------------------------------------------
__global__ __launch_bounds__(256) void sigma_kernel(
    const float* __restrict__ vA, const float* __restrict__ vB,
    const float* __restrict__ uA, const float* __restrict__ uB,
    float* __restrict__ sig) {
  float s[4] = {0.f, 0.f, 0.f, 0.f};
  for (int i = threadIdx.x; i < KCAT; i += 256) {
    s[0] += vA[i] * vB[i];
    s[1] += vA[i] * vA[i];
  }
  for (int i = threadIdx.x; i < D_LAT; i += 256) {
    s[2] += uA[i] * uA[i];
    s[3] += uA[i] * uB[i];
  }
  __shared__ float red[4][4];
  int lane = threadIdx.x & 63, w = threadIdx.x >> 6;
  for (int k = 0; k < 4; k++) {
    float a = s[k];
    for (int off = 32; off; off >>= 1) a += __shfl_down(a, off, 64);
    if (lane == 0) red[k][w] = a;
  }
  __syncthreads();
  if (threadIdx.x == 0) {
    float d0 = red[0][0] + red[0][1] + red[0][2] + red[0][3];
    float d1 = red[1][0] + red[1][1] + red[1][2] + red[1][3];
    float d2 = red[2][0] + red[2][1] + red[2][2] + red[2][3];
    float d3 = red[3][0] + red[3][1] + red[3][2] + red[3][3];
    sig[0] = sqrtf(0.25f * d0 / d1);
    sig[1] = sqrtf(0.25f * d2 / d3);
  }
}

// ---------------- fold sigma into bf16 weights -----------------------------
__global__ void wfold_kernel(const float* __restrict__ W1,
                             const float* __restrict__ W2,
                             const float* __restrict__ sig,
                             __hip_bfloat16* __restrict__ W1b,
                             __hip_bfloat16* __restrict__ W2b) {
  int i = blockIdx.x * 256 + threadIdx.x;
  if (i < D_HID * KCAT) W1b[i] = __float2bfloat16(W1[i] * sig[0]);
  int j = i - D_HID * KCAT;
  if (j >= 0 && j < D_LAT * D_HID) W2b[j] = __float2bfloat16(W2[j] * sig[1]);
}

// ---------------- warm-up fusions ------------------------------------------
__global__ void warm1_kernel(const float* __restrict__ Fh,
                             float* __restrict__ Xh,
                             __hip_bfloat16* __restrict__ zc) {
  int i = blockIdx.x * 256 + threadIdx.x;
  float v = Fh[i];
  Xh[SLOT + i] = v;
  zc[(i >> 8) * KCAT + (i & 255)] = __float2bfloat16(v);
}
__global__ void warm2_kernel(const float* __restrict__ Fh,
                             float* __restrict__ Xh, float* __restrict__ Fw) {
  int i = blockIdx.x * 256 + threadIdx.x;
  Xh[2 * SLOT + i] = Fh[i];
  Fw[2 * SLOT + i] = Fh[SLOT + i];
}

// ---------------- bf16 MFMA GEMM: C = tanh(A @ W^T + bias) -----------------
template <int BM, int BN, bool OUT_BF16>
__global__ __launch_bounds__(256) void gemm_mfma(
    const __hip_bfloat16* __restrict__ A, const __hip_bfloat16* __restrict__ W,
    int K, const float* __restrict__ bias, float* __restrict__ Cf,
    __hip_bfloat16* __restrict__ Cb, int N) {
  __shared__ __align__(16) u16 lds[(BM + BN) * 64];
  u16* As = lds;
  u16* Ws = lds + BM * 64;
  const int tid = threadIdx.x;
  const int lane = tid & 63;
  const int wid = tid >> 6;
  const int wy = wid >> 1, wx = wid & 1;
  constexpr int WM = BM / 2, WN = BN / 2;
  constexpr int MB = WM / 16, NB = WN / 16;
  const int bm = blockIdx.x * BM;
  const int bn = blockIdx.y * BN;
  const int rlo = lane & 15, quad = lane >> 4;

  f32x4 acc[MB][NB] = {};

  for (int k0 = 0; k0 < K; k0 += 64) {
    for (int c = tid; c < BM * 8; c += 256) {
      int r = c >> 3, o = (c & 7) ^ (r & 7);
      __builtin_amdgcn_global_load_lds(
          (const __attribute__((address_space(1))) void*)(A + (size_t)(bm + r) * K + k0 + o * 8),
          (__attribute__((address_space(3))) void*)(As + c * 8), 16, 0, 0);
    }
    for (int c = tid; c < BN * 8; c += 256) {
      int r = c >> 3, o = (c & 7) ^ (r & 7);
      __builtin_amdgcn_global_load_lds(
          (const __attribute__((address_space(1))) void*)(W + (size_t)(bn + r) * K + k0 + o * 8),
          (__attribute__((address_space(3))) void*)(Ws + c * 8), 16, 0, 0);
    }
    __syncthreads();
#pragma unroll
    for (int kk = 0; kk < 2; kk++) {
      bf16x8 af[MB], bfr[NB];
#pragma unroll
      for (int mb = 0; mb < MB; mb++) {
        int r = wy * WM + mb * 16 + rlo;
        int o = (kk * 4 + quad) ^ (r & 7);
        af[mb] = *(const bf16x8*)(As + (r * 8 + o) * 8);
      }
#pragma unroll
      for (int nb = 0; nb < NB; nb++) {
        int r = wx * WN + nb * 16 + rlo;
        int o = (kk * 4 + quad) ^ (r & 7);
        bfr[nb] = *(const bf16x8*)(Ws + (r * 8 + o) * 8);
      }
#pragma unroll
      for (int mb = 0; mb < MB; mb++)
#pragma unroll
        for (int nb = 0; nb < NB; nb++)
          acc[mb][nb] = __builtin_amdgcn_mfma_f32_16x16x32_bf16(
              af[mb], bfr[nb], acc[mb][nb], 0, 0, 0);
    }
    __syncthreads();
  }

#pragma unroll
  for (int mb = 0; mb < MB; mb++) {
#pragma unroll
    for (int nb = 0; nb < NB; nb++) {
      int n = bn + wx * WN + nb * 16 + rlo;
      float bv = bias[n];
#pragma unroll
      for (int rg = 0; rg < 4; rg++) {
        int m = bm + wy * WM + mb * 16 + quad * 4 + rg;
        float val = tanhf(acc[mb][nb][rg] + bv);
        if constexpr (OUT_BF16) {
          Cb[(size_t)m * N + n] = __float2bfloat16(val);
        } else {
          Cf[(size_t)m * N + n] = val;
        }
      }
    }
  }
}

// ---------------- standalone Anderson step (t=3 only, MK=2) ----------------
template <int MK>
__global__ __launch_bounds__(256) void anderson_step_kernel(
    const float* __restrict__ Xh, const float* __restrict__ Fh,
    float* __restrict__ Xw, __hip_bfloat16* __restrict__ zc, int t) {
  const int lane = threadIdx.x & 63;
  const int wid = threadIdx.x >> 6;
  const int b = blockIdx.x * 4 + wid;
  const int base = b * D_LAT + 4 * lane;

  const int sl0 = (t - 1) % NRING;
  f32x4 fa = *(const f32x4*)(Fh + (size_t)sl0 * SLOT + base);
  f32x4 xa = *(const f32x4*)(Xh + (size_t)sl0 * SLOT + base);
  const f32x4 Fm1 = fa;
  const f32x4 r = fa - xa;

  f32x4 dF[MK], dG[MK];
#pragma unroll
  for (int i = 1; i <= MK; i++) {
    int s2 = (t - 1 - i) % NRING;
    f32x4 fb = *(const f32x4*)(Fh + (size_t)s2 * SLOT + base);
    f32x4 xb = *(const f32x4*)(Xh + (size_t)s2 * SLOT + base);
    dF[i - 1] = fa - fb;
    dG[i - 1] = dF[i - 1] - (xa - xb);
    fa = fb;
    xa = xb;
  }

  constexpr int NV = MK * (MK + 1) / 2 + MK;
  float vals[NV];
  {
    int p = 0;
#pragma unroll
    for (int i = 0; i < MK; i++)
#pragma unroll
      for (int j = i; j < MK; j++) {
        f32x4 q = dG[i] * dG[j];
        vals[p++] = q[0] + q[1] + q[2] + q[3];
      }
#pragma unroll
    for (int i = 0; i < MK; i++) {
      f32x4 q = dG[i] * r;
      vals[p++] = q[0] + q[1] + q[2] + q[3];
    }
  }
#pragma unroll
  for (int off = 1; off <= 32; off <<= 1)
#pragma unroll
    for (int v = 0; v < NV; v++) vals[v] += __shfl_xor(vals[v], off, 64);

  double A[MK][MK], bv[MK], alpha[MK];
  {
    int p = 0;
#pragma unroll
    for (int i = 0; i < MK; i++)
#pragma unroll
      for (int j = i; j < MK; j++) {
        A[i][j] = (double)vals[p];
        A[j][i] = (double)vals[p];
        p++;
      }
#pragma unroll
    for (int i = 0; i < MK; i++) A[i][i] += (double)1e-4f;
#pragma unroll
    for (int i = 0; i < MK; i++) bv[i] = (double)vals[p++];
  }

#pragma unroll
  for (int c = 0; c < MK; c++) {
    double inv = 1.0 / A[c][c];
#pragma unroll
    for (int rr = c + 1; rr < MK; rr++) {
      double fct = A[rr][c] * inv;
#pragma unroll
      for (int cc = c; cc < MK; cc++) A[rr][cc] -= fct * A[c][cc];
      bv[rr] -= fct * bv[c];
    }
  }
#pragma unroll
  for (int i = MK - 1; i >= 0; i--) {
    double s = bv[i];
#pragma unroll
    for (int j = i + 1; j < MK; j++) s -= A[i][j] * alpha[j];
    alpha[i] = s / A[i][i];
  }

  f32x4 x = Fm1;
#pragma unroll
  for (int i = 0; i < MK; i++) x -= dF[i] * (float)alpha[i];
  *(f32x4*)(Xw + base) = x;
  if (zc != nullptr) {
    union { __hip_bfloat16 h[4]; unsigned long long u; } cv;
#pragma unroll
    for (int j = 0; j < 4; j++) cv.h[j] = __float2bfloat16(x[j]);
    *(unsigned long long*)(zc + (size_t)b * KCAT + 4 * lane) = cv.u;
  }
}

// ---------------- FUSED gemm2 + Anderson(t) --------------------------------
// Grid 128 x 512 thr (8 waves). Block bm = 16 rows, BN = 256 (full width).
// Phase 1: F[t-1] rows = tanh(hb @ W2b^T + b2), K=1024 (same BK=64 / kk
//   order as the plain gemm2 -> identical rounding). Written to global ring
//   slot (t-1)%7 AND to LDS Fs.
// Phase 2: Anderson step t for the same 16 rows. wave w handles rows
//   {2w, 2w+1} sequentially; F[t-1] read from LDS, older history global.
//   f32 solve (reference uses f32 LU).
template <int MK, bool LAST>
__global__ __launch_bounds__(512, 4) void gemm2_anderson_kernel(
    const __hip_bfloat16* __restrict__ hb, const __hip_bfloat16* __restrict__ W2b,
    const float* __restrict__ b2, float* __restrict__ Fh,
    float* __restrict__ Xh, float* __restrict__ Xw,
    __hip_bfloat16* __restrict__ zc, int t) {
  __shared__ __align__(16) u16 lds[(16 + 256) * 64];
  __shared__ __align__(16) float Fs[16][272];
  u16* As = lds;             // hb tile: 16 rows x 64
  u16* Ws = lds + 16 * 64;   // W2 tile: 256 rows x 64
  const int tid = threadIdx.x;
  const int lane = tid & 63;
  const int w = tid >> 6;          // 0..7
  const int rlo = lane & 15, quad = lane >> 4;
  const int bm = blockIdx.x * 16;

  f32x4 acc[2] = {};
  for (int k0 = 0; k0 < 1024; k0 += 64) {
    if (tid < 128) {
      int r = tid >> 3, o = (tid & 7) ^ (r & 7);
      __builtin_amdgcn_global_load_lds(
          (const __attribute__((address_space(1))) void*)(hb + (size_t)(bm + r) * 1024 + k0 + o * 8),
          (__attribute__((address_space(3))) void*)(As + tid * 8), 16, 0, 0);
    }
    for (int c = tid; c < 2048; c += 512) {
      int r = c >> 3, o = (c & 7) ^ (r & 7);
      __builtin_amdgcn_global_load_lds(
          (const __attribute__((address_space(1))) void*)(W2b + (size_t)r * 1024 + k0 + o * 8),
          (__attribute__((address_space(3))) void*)(Ws + c * 8), 16, 0, 0);
    }
    __syncthreads();
#pragma unroll
    for (int kk = 0; kk < 2; kk++) {
      int oa = (kk * 4 + quad) ^ (rlo & 7);
      bf16x8 af = *(const bf16x8*)(As + (rlo * 8 + oa) * 8);
#pragma unroll
      for (int nb = 0; nb < 2; nb++) {
        int r2 = 32 * w + nb * 16 + rlo;
        int ob = (kk * 4 + quad) ^ (r2 & 7);
        bf16x8 bf = *(const bf16x8*)(Ws + (r2 * 8 + ob) * 8);
        acc[nb] = __builtin_amdgcn_mfma_f32_16x16x32_bf16(af, bf, acc[nb], 0, 0, 0);
      }
    }
    __syncthreads();
  }

  // epilogue: bias + tanh -> global ring + LDS
  float* Fout = Fh + (size_t)((t - 1) % NRING) * SLOT;
#pragma unroll
  for (int nb = 0; nb < 2; nb++) {
    int n = 32 * w + nb * 16 + rlo;
    float bvv = b2[n];
#pragma unroll
    for (int rg = 0; rg < 4; rg++) {
      int m = quad * 4 + rg;
      float val = tanhf(acc[nb][rg] + bvv);
      Fout[(size_t)(bm + m) * 256 + n] = val;
      Fs[m][n] = val;
    }
  }
  __syncthreads();

  // Anderson step t: wave w -> rows 2w, 2w+1 (sequential to cap VGPR)
#pragma unroll 1
  for (int rr = 0; rr < 2; rr++) {
    const int row = 2 * w + rr;
    const int base = (bm + row) * D_LAT + 4 * lane;

    f32x4 fa = *(const f32x4*)&Fs[row][4 * lane];
    const f32x4 Fm1 = fa;
    f32x4 xa = *(const f32x4*)(Xh + (size_t)((t - 1) % NRING) * SLOT + base);
    const f32x4 r = fa - xa;

    f32x4 dF[MK], dG[MK];
#pragma unroll
    for (int i = 1; i <= MK; i++) {
      int s2 = (t - 1 - i) % NRING;
      f32x4 fb = *(const f32x4*)(Fh + (size_t)s2 * SLOT + base);
      f32x4 xb = *(const f32x4*)(Xh + (size_t)s2 * SLOT + base);
      dF[i - 1] = fa - fb;
      dG[i - 1] = dF[i - 1] - (xa - xb);
      fa = fb;
      xa = xb;
    }

    constexpr int NV = MK * (MK + 1) / 2 + MK;
    float vals[NV];
    {
      int p = 0;
#pragma unroll
      for (int i = 0; i < MK; i++)
#pragma unroll
        for (int j = i; j < MK; j++) {
          f32x4 q = dG[i] * dG[j];
          vals[p++] = q[0] + q[1] + q[2] + q[3];
        }
#pragma unroll
      for (int i = 0; i < MK; i++) {
        f32x4 q = dG[i] * r;
        vals[p++] = q[0] + q[1] + q[2] + q[3];
      }
    }
#pragma unroll
    for (int off = 1; off <= 32; off <<= 1)
#pragma unroll
      for (int v = 0; v < NV; v++) vals[v] += __shfl_xor(vals[v], off, 64);

    float A[MK][MK], bv[MK], alpha[MK];
    {
      int p = 0;
#pragma unroll
      for (int i = 0; i < MK; i++)
#pragma unroll
        for (int j = i; j < MK; j++) {
          A[i][j] = vals[p];
          A[j][i] = vals[p];
          p++;
        }
#pragma unroll
      for (int i = 0; i < MK; i++) A[i][i] += 1e-4f;
#pragma unroll
      for (int i = 0; i < MK; i++) bv[i] = vals[p++];
    }

#pragma unroll
    for (int c = 0; c < MK; c++) {
      float inv = 1.0f / A[c][c];
#pragma unroll
      for (int r2 = c + 1; r2 < MK; r2++) {
        float fct = A[r2][c] * inv;
#pragma unroll
        for (int cc = c; cc < MK; cc++) A[r2][cc] -= fct * A[c][cc];
        bv[r2] -= fct * bv[c];
      }
    }
#pragma unroll
    for (int i = MK - 1; i >= 0; i--) {
      float s = bv[i];
#pragma unroll
      for (int j = i + 1; j < MK; j++) s -= A[i][j] * alpha[j];
      alpha[i] = s / A[i][i];
    }

    f32x4 x = Fm1;
#pragma unroll
    for (int i = 0; i < MK; i++) x -= dF[i] * alpha[i];
    *(f32x4*)(Xw + base) = x;
    if constexpr (!LAST) {
      union { __hip_bfloat16 h[4]; unsigned long long u; } cv;
#pragma unroll
      for (int j = 0; j < 4; j++) cv.h[j] = __float2bfloat16(x[j]);
      *(unsigned long long*)(zc + (size_t)(bm + row) * KCAT + 4 * lane) = cv.u;
    }
  }
}

// ---------------- host orchestration ---------------------------------------
static void eval_f(const __hip_bfloat16* zc, const __hip_bfloat16* W1b,
                   const __hip_bfloat16* W2b, const float* b1, const float* b2,
                   __hip_bfloat16* hb, float* Fout, hipStream_t stream) {
  gemm_mfma<64, 64, true><<<dim3(B_ROWS / 64, D_HID / 64), 256, 0, stream>>>(
      zc, W1b, KCAT, b1, nullptr, hb, D_HID);
  gemm_mfma<32, 32, false><<<dim3(B_ROWS / 32, D_LAT / 32), 256, 0, stream>>>(
      hb, W2b, D_HID, b2, Fout, nullptr, D_LAT);
}

extern "C" void kernel_launch(void* const* d_in, const int* in_sizes, int n_in,
                              void* d_out, int out_size, void* d_ws,
                              size_t ws_size, hipStream_t stream) {
  const float* ctx = (const float*)d_in[0];
  const float* W1 = (const float*)d_in[1];
  const float* b1 = (const float*)d_in[2];
  const float* W2 = (const float*)d_in[3];
  const float* b2 = (const float*)d_in[4];
  float* out = (float*)d_out;

  float* ws = (float*)d_ws;
  float* sig = ws;                       // 16
  float* vA = ws + 16;                   // 512
  float* vB = vA + KCAT;                 // 512
  float* uA = vB + KCAT;                 // 256
  float* uB = uA + D_LAT;                // 256
  float* G1p = uB + D_LAT;               // 512*512
  float* G2 = G1p + KCAT * KCAT;         // 256*256
  float* Xh = G2 + D_LAT * D_LAT;        // 7*SLOT
  float* Fh = Xh + NRING * SLOT;         // 7*SLOT
  __hip_bfloat16* W1b = (__hip_bfloat16*)(Fh + NRING * SLOT);  // 524288
  __hip_bfloat16* W2b = W1b + D_HID * KCAT;                    // 262144
  __hip_bfloat16* zc = W2b + D_LAT * D_HID;                    // 2048*512
  __hip_bfloat16* hb = zc + B_ROWS * KCAT;                     // 2048*1024
  // ~38.5 MB total

  init_kernel<<<(B_ROWS * KCAT + 255) / 256, 256, 0, stream>>>(ctx, zc, vA, uA,
                                                               G1p, G2);
  // Gram (1024 + 256) + colsum (64)
  gram_kernel<<<1344, 256, 0, stream>>>(W1, W2, G1p, G2, vA);

  for (int it = 1; it <= 21; it++) {
    const float* vi; float* vo;
    const float* ui; float* uo;
    if (it & 1) { vi = vB; vo = vA; ui = uA; uo = uB; }
    else        { vi = vA; vo = vB; ui = uB; uo = uA; }
    pmv_kernel<<<192, 256, 0, stream>>>(G1p, G2, vi, vo, ui, uo, it >= 2);
  }
  sigma_kernel<<<1, 256, 0, stream>>>(vA, vB, uA, uB, sig);
  wfold_kernel<<<(D_HID * KCAT + D_LAT * D_HID + 255) / 256, 256, 0, stream>>>(
      W1, W2, sig, W1b, W2b);

  hipMemsetAsync(Xh, 0, SLOT * sizeof(float), stream);

  // warm-up: F0, F1, F2 (plain gemm2), then standalone anderson(3)
  eval_f(zc, W1b, W2b, b1, b2, hb, Fh, stream);
  warm1_kernel<<<SLOT / 256, 256, 0, stream>>>(Fh, Xh, zc);
  eval_f(zc, W1b, W2b, b1, b2, hb, Fh + SLOT, stream);
  warm2_kernel<<<SLOT / 256, 256, 0, stream>>>(Fh, Xh, Fh);
  anderson_step_kernel<2><<<B_ROWS / 4, 256, 0, stream>>>(
      Xh, Fh, Xh + (3 % NRING) * SLOT, zc, 3);

  // loop: t = 3..24: gemm1(x_t) then fused [gemm2 -> F[t]] + [anderson(t+1)]
  for (int t = 3; t <= 24; t++) {
    gemm_mfma<64, 64, true><<<dim3(B_ROWS / 64, D_HID / 64), 256, 0, stream>>>(
        zc, W1b, KCAT, b1, nullptr, hb, D_HID);
    int tn = t + 1;
    int mk = (tn - 1 < 5) ? tn - 1 : 5;
    float* Xw = (tn == 25) ? out : (Xh + (tn % NRING) * SLOT);
    dim3 g(B_ROWS / 16);
    if (tn == 25)
      gemm2_anderson_kernel<5, true><<<g, 512, 0, stream>>>(
          hb, W2b, b2, Fh, Xh, Xw, nullptr, tn);
    else if (mk == 3)
      gemm2_anderson_kernel<3, false><<<g, 512, 0, stream>>>(
          hb, W2b, b2, Fh, Xh, Xw, zc, tn);
    else if (mk == 4)
      gemm2_anderson_kernel<4, false><<<g, 512, 0, stream>>>(
          hb, W2b, b2, Fh, Xh, Xw, zc, tn);
    else
      gemm2_anderson_kernel<5, false><<<g, 512, 0, stream>>>(
          hb, W2b, b2, Fh, Xh, Xw, zc, tn);
  }
}

// Round 6
// 874.079 us; speedup vs baseline: 1.1401x; 1.1401x over previous
//
#include <hip/hip_runtime.h>
#include <hip/hip_bf16.h>

// ---------------------------------------------------------------------------
// DEQ layer, MI355X round 10.
//  - REVERT round-9 gemm2+anderson fusion: __launch_bounds__(512,4) capped
//    VGPR at 128 -> MK=5 state spilled (rule-20 regression), and 128-block
//    grid left half the GPU idle. Back to round-8 separate kernels (813us).
//  - anderson_step v3: row split across 2 waves (f32x2/lane). 2048 rows =
//    2048 waves was only 2 waves/SIMD (latency-bound, 14.7us vs 4.5us
//    roofline). 4096 waves = 4/SIMD; halves combine 20 partials via LDS;
//    f32 solve (proved same absmax in round 9), VGPR ~100 < 128 cap.
//  - gram keeps colsum fused as mode-C blocks (1344 blocks total).
//  - power chain: 21 pmv launches + sigma + wfold (grid barriers lose).
//  - GEMMs: bf16 MFMA 16x16x32, gemm1 64x64 (512 blk), gemm2 32x32 (512 blk).
// ---------------------------------------------------------------------------

#define B_ROWS 2048
#define D_LAT  256
#define D_CTX  256
#define D_HID  1024
#define KCAT   512
#define SLOT   (B_ROWS * D_LAT)
#define NRING  7

typedef __bf16 bf16x8 __attribute__((ext_vector_type(8)));
typedef float f32x4 __attribute__((ext_vector_type(4)));
typedef float f32x2 __attribute__((ext_vector_type(2)));
typedef unsigned short u16;

// ---------------- init: zc = [bf16(0)|bf16(ctx)], uA=1, vA=0, G=0 ----------
__global__ void init_kernel(const float* __restrict__ ctx,
                            __hip_bfloat16* __restrict__ zc,
                            float* __restrict__ vA, float* __restrict__ uA,
                            float* __restrict__ G1p, float* __restrict__ G2) {
  int i = blockIdx.x * 256 + threadIdx.x;
  if (i < B_ROWS * KCAT) {
    int b = i >> 9, c = i & 511;
    float v = (c < 256) ? 0.0f : ctx[b * 256 + (c - 256)];
    zc[i] = __float2bfloat16(v);
  }
  if (i < 512 * 512) G1p[i] = 0.0f;
  if (i < 256 * 256) G2[i] = 0.0f;
  if (i < KCAT) vA[i] = 0.0f;
  if (i < D_LAT) uA[i] = 1.0f;
}

// ---------------- Gram build + colsum, split-K x8, 64x32 tiles -------------
// blocks 0..1023:   G1' = W1^T W1 (mode A)
// blocks 1024..1279: G2 = W2 W2^T (mode B)
// blocks 1280..1343: colsum partials vA += W1^T ones (mode C)
__global__ __launch_bounds__(256) void gram_kernel(
    const float* __restrict__ W1, const float* __restrict__ W2,
    float* __restrict__ G1p, float* __restrict__ G2,
    float* __restrict__ vA) {
  __shared__ float As[32][66];
  __shared__ float Bs[32][34];
  const int tid = threadIdx.x;
  const int tx = tid & 15, ty = tid >> 4;

  int b = blockIdx.x;
  if (b >= 1280) {  // mode C: colsum
    int cb = b - 1280;
    for (int c = tid; c < KCAT; c += 256) {
      float s = 0.f;
#pragma unroll
      for (int r = 0; r < 16; r++) s += W1[(size_t)(16 * cb + r) * KCAT + c];
      atomicAdd(&vA[c], s);
    }
    return;
  }

  const float* X; float* G; int N, ti, tj, k0base; bool modeA;
  if (b < 1024) {
    modeA = true; X = W1; G = G1p; N = 512;
    int s = b >> 7, t = b & 127;
    ti = t >> 4; tj = t & 15; k0base = s * 128;
  } else {
    modeA = false; b -= 1024; X = W2; G = G2; N = 256;
    int s = b >> 5, t = b & 31;
    ti = t >> 3; tj = t & 7; k0base = s * 128;
  }

  float acc[4][2] = {};
  for (int k0 = k0base; k0 < k0base + 128; k0 += 32) {
    if (modeA) {
      for (int idx = tid; idx < 2048; idx += 256) {
        int r = idx & 63, c = idx >> 6;
        As[c][r] = X[(size_t)(k0 + c) * 512 + ti * 64 + r];
      }
      for (int idx = tid; idx < 1024; idx += 256) {
        int r = idx & 31, c = idx >> 5;
        Bs[c][r] = X[(size_t)(k0 + c) * 512 + tj * 32 + r];
      }
    } else {
      for (int idx = tid; idx < 2048; idx += 256) {
        int c = idx & 31, r = idx >> 5;
        As[c][r] = X[(size_t)(ti * 64 + r) * 1024 + k0 + c];
      }
      for (int idx = tid; idx < 1024; idx += 256) {
        int c = idx & 31, r = idx >> 5;
        Bs[c][r] = X[(size_t)(tj * 32 + r) * 1024 + k0 + c];
      }
    }
    __syncthreads();
#pragma unroll
    for (int kk = 0; kk < 32; kk++) {
      const float2* ap = (const float2*)&As[kk][ty * 4];
      float2 a0 = ap[0], a1 = ap[1];
      float2 b0 = *(const float2*)&Bs[kk][tx * 2];
      float a[4] = {a0.x, a0.y, a1.x, a1.y};
      float bb[2] = {b0.x, b0.y};
#pragma unroll
      for (int i = 0; i < 4; i++)
#pragma unroll
        for (int j = 0; j < 2; j++) acc[i][j] += a[i] * bb[j];
    }
    __syncthreads();
  }
#pragma unroll
  for (int i = 0; i < 4; i++)
#pragma unroll
    for (int j = 0; j < 2; j++)
      atomicAdd(&G[(size_t)(ti * 64 + ty * 4 + i) * N + tj * 32 + tx * 2 + j],
                acc[i][j]);
}

// ---------------- joint power matvec: out = 0.25 * G in --------------------
__global__ __launch_bounds__(256) void pmv_kernel(
    const float* __restrict__ G1p, const float* __restrict__ G2,
    const float* __restrict__ vi, float* __restrict__ vo,
    const float* __restrict__ ui, float* __restrict__ uo, int g1_active) {
  int gw = blockIdx.x * 4 + (threadIdx.x >> 6);
  int lane = threadIdx.x & 63;
  const float* G; const float* in; float* out; int n, r;
  if (gw < 512) {
    if (!g1_active) return;
    G = G1p; in = vi; out = vo; n = 512; r = gw;
  } else {
    G = G2; in = ui; out = uo; n = 256; r = gw - 512;
  }
  const float4* Gr = (const float4*)(G + (size_t)r * n);
  const float4* uv = (const float4*)in;
  float acc = 0.f;
  for (int c = lane; c < (n >> 2); c += 64) {
    float4 g = Gr[c], u = uv[c];
    acc += g.x * u.x + g.y * u.y + g.z * u.z + g.w * u.w;
  }
  for (int off = 32; off; off >>= 1) acc += __shfl_down(acc, off, 64);
  if (lane == 0) out[r] = 0.25f * acc;
}

// ---------------- sigma ----------------------------------------------------
__global__ __launch_bounds__(256) void sigma_kernel(
    const float* __restrict__ vA, const float* __restrict__ vB,
    const float* __restrict__ uA, const float* __restrict__ uB,
    float* __restrict__ sig) {
  float s[4] = {0.f, 0.f, 0.f, 0.f};
  for (int i = threadIdx.x; i < KCAT; i += 256) {
    s[0] += vA[i] * vB[i];
    s[1] += vA[i] * vA[i];
  }
  for (int i = threadIdx.x; i < D_LAT; i += 256) {
    s[2] += uA[i] * uA[i];
    s[3] += uA[i] * uB[i];
  }
  __shared__ float red[4][4];
  int lane = threadIdx.x & 63, w = threadIdx.x >> 6;
  for (int k = 0; k < 4; k++) {
    float a = s[k];
    for (int off = 32; off; off >>= 1) a += __shfl_down(a, off, 64);
    if (lane == 0) red[k][w] = a;
  }
  __syncthreads();
  if (threadIdx.x == 0) {
    float d0 = red[0][0] + red[0][1] + red[0][2] + red[0][3];
    float d1 = red[1][0] + red[1][1] + red[1][2] + red[1][3];
    float d2 = red[2][0] + red[2][1] + red[2][2] + red[2][3];
    float d3 = red[3][0] + red[3][1] + red[3][2] + red[3][3];
    sig[0] = sqrtf(0.25f * d0 / d1);
    sig[1] = sqrtf(0.25f * d2 / d3);
  }
}

// ---------------- fold sigma into bf16 weights -----------------------------
__global__ void wfold_kernel(const float* __restrict__ W1,
                             const float* __restrict__ W2,
                             const float* __restrict__ sig,
                             __hip_bfloat16* __restrict__ W1b,
                             __hip_bfloat16* __restrict__ W2b) {
  int i = blockIdx.x * 256 + threadIdx.x;
  if (i < D_HID * KCAT) W1b[i] = __float2bfloat16(W1[i] * sig[0]);
  int j = i - D_HID * KCAT;
  if (j >= 0 && j < D_LAT * D_HID) W2b[j] = __float2bfloat16(W2[j] * sig[1]);
}

// ---------------- warm-up fusions ------------------------------------------
__global__ void warm1_kernel(const float* __restrict__ Fh,
                             float* __restrict__ Xh,
                             __hip_bfloat16* __restrict__ zc) {
  int i = blockIdx.x * 256 + threadIdx.x;
  float v = Fh[i];
  Xh[SLOT + i] = v;
  zc[(i >> 8) * KCAT + (i & 255)] = __float2bfloat16(v);
}
__global__ void warm2_kernel(const float* __restrict__ Fh,
                             float* __restrict__ Xh, float* __restrict__ Fw) {
  int i = blockIdx.x * 256 + threadIdx.x;
  Xh[2 * SLOT + i] = Fh[i];
  Fw[2 * SLOT + i] = Fh[SLOT + i];
}

// ---------------- bf16 MFMA GEMM: C = tanh(A @ W^T + bias) -----------------
template <int BM, int BN, bool OUT_BF16>
__global__ __launch_bounds__(256) void gemm_mfma(
    const __hip_bfloat16* __restrict__ A, const __hip_bfloat16* __restrict__ W,
    int K, const float* __restrict__ bias, float* __restrict__ Cf,
    __hip_bfloat16* __restrict__ Cb, int N) {
  __shared__ __align__(16) u16 lds[(BM + BN) * 64];
  u16* As = lds;
  u16* Ws = lds + BM * 64;
  const int tid = threadIdx.x;
  const int lane = tid & 63;
  const int wid = tid >> 6;
  const int wy = wid >> 1, wx = wid & 1;
  constexpr int WM = BM / 2, WN = BN / 2;
  constexpr int MB = WM / 16, NB = WN / 16;
  const int bm = blockIdx.x * BM;
  const int bn = blockIdx.y * BN;
  const int rlo = lane & 15, quad = lane >> 4;

  f32x4 acc[MB][NB] = {};

  for (int k0 = 0; k0 < K; k0 += 64) {
    for (int c = tid; c < BM * 8; c += 256) {
      int r = c >> 3, o = (c & 7) ^ (r & 7);
      __builtin_amdgcn_global_load_lds(
          (const __attribute__((address_space(1))) void*)(A + (size_t)(bm + r) * K + k0 + o * 8),
          (__attribute__((address_space(3))) void*)(As + c * 8), 16, 0, 0);
    }
    for (int c = tid; c < BN * 8; c += 256) {
      int r = c >> 3, o = (c & 7) ^ (r & 7);
      __builtin_amdgcn_global_load_lds(
          (const __attribute__((address_space(1))) void*)(W + (size_t)(bn + r) * K + k0 + o * 8),
          (__attribute__((address_space(3))) void*)(Ws + c * 8), 16, 0, 0);
    }
    __syncthreads();
#pragma unroll
    for (int kk = 0; kk < 2; kk++) {
      bf16x8 af[MB], bfr[NB];
#pragma unroll
      for (int mb = 0; mb < MB; mb++) {
        int r = wy * WM + mb * 16 + rlo;
        int o = (kk * 4 + quad) ^ (r & 7);
        af[mb] = *(const bf16x8*)(As + (r * 8 + o) * 8);
      }
#pragma unroll
      for (int nb = 0; nb < NB; nb++) {
        int r = wx * WN + nb * 16 + rlo;
        int o = (kk * 4 + quad) ^ (r & 7);
        bfr[nb] = *(const bf16x8*)(Ws + (r * 8 + o) * 8);
      }
#pragma unroll
      for (int mb = 0; mb < MB; mb++)
#pragma unroll
        for (int nb = 0; nb < NB; nb++)
          acc[mb][nb] = __builtin_amdgcn_mfma_f32_16x16x32_bf16(
              af[mb], bfr[nb], acc[mb][nb], 0, 0, 0);
    }
    __syncthreads();
  }

#pragma unroll
  for (int mb = 0; mb < MB; mb++) {
#pragma unroll
    for (int nb = 0; nb < NB; nb++) {
      int n = bn + wx * WN + nb * 16 + rlo;
      float bv = bias[n];
#pragma unroll
      for (int rg = 0; rg < 4; rg++) {
        int m = bm + wy * WM + mb * 16 + quad * 4 + rg;
        float val = tanhf(acc[mb][nb][rg] + bv);
        if constexpr (OUT_BF16) {
          Cb[(size_t)m * N + n] = __float2bfloat16(val);
        } else {
          Cf[(size_t)m * N + n] = val;
        }
      }
    }
  }
}

// ---------------- Anderson step v3: 2 waves per row (4 waves/SIMD) ---------
// Grid B_ROWS/2 x 256 thr. Wave w: row = 2*blk + (w>>1), half = w&1;
// lane owns elems [half*128 + 2*lane, +2) as f32x2. Each half butterfly-
// reduces its 20 partials, halves combine via LDS, f32 solve redundant.
template <int MK>
__global__ __launch_bounds__(256, 4) void anderson_step_kernel(
    const float* __restrict__ Xh, const float* __restrict__ Fh,
    float* __restrict__ Xw, __hip_bfloat16* __restrict__ zc, int t) {
  const int lane = threadIdx.x & 63;
  const int w = threadIdx.x >> 6;
  const int half = w & 1, rowi = w >> 1;
  const int b = blockIdx.x * 2 + rowi;
  const int base = b * D_LAT + half * 128 + 2 * lane;

  const int sl0 = (t - 1) % NRING;
  f32x2 fa = *(const f32x2*)(Fh + (size_t)sl0 * SLOT + base);
  f32x2 xa = *(const f32x2*)(Xh + (size_t)sl0 * SLOT + base);
  const f32x2 Fm1 = fa;
  const f32x2 r = fa - xa;

  f32x2 dF[MK], dG[MK];
#pragma unroll
  for (int i = 1; i <= MK; i++) {
    int s2 = (t - 1 - i) % NRING;
    f32x2 fb = *(const f32x2*)(Fh + (size_t)s2 * SLOT + base);
    f32x2 xb = *(const f32x2*)(Xh + (size_t)s2 * SLOT + base);
    dF[i - 1] = fa - fb;
    dG[i - 1] = dF[i - 1] - (xa - xb);
    fa = fb;
    xa = xb;
  }

  constexpr int NV = MK * (MK + 1) / 2 + MK;
  float vals[NV];
  {
    int p = 0;
#pragma unroll
    for (int i = 0; i < MK; i++)
#pragma unroll
      for (int j = i; j < MK; j++) {
        f32x2 q = dG[i] * dG[j];
        vals[p++] = q[0] + q[1];
      }
#pragma unroll
    for (int i = 0; i < MK; i++) {
      f32x2 q = dG[i] * r;
      vals[p++] = q[0] + q[1];
    }
  }
#pragma unroll
  for (int off = 1; off <= 32; off <<= 1)
#pragma unroll
    for (int v = 0; v < NV; v++) vals[v] += __shfl_xor(vals[v], off, 64);

  // combine the two halves of each row via LDS (320 B)
  __shared__ float lv[2][2][NV];
  if (lane == 0) {
#pragma unroll
    for (int v = 0; v < NV; v++) lv[rowi][half][v] = vals[v];
  }
  __syncthreads();
#pragma unroll
  for (int v = 0; v < NV; v++) vals[v] = lv[rowi][0][v] + lv[rowi][1][v];

  float A[MK][MK], bv[MK], alpha[MK];
  {
    int p = 0;
#pragma unroll
    for (int i = 0; i < MK; i++)
#pragma unroll
      for (int j = i; j < MK; j++) {
        A[i][j] = vals[p];
        A[j][i] = vals[p];
        p++;
      }
#pragma unroll
    for (int i = 0; i < MK; i++) A[i][i] += 1e-4f;
#pragma unroll
    for (int i = 0; i < MK; i++) bv[i] = vals[p++];
  }

#pragma unroll
  for (int c = 0; c < MK; c++) {
    float inv = 1.0f / A[c][c];
#pragma unroll
    for (int rr = c + 1; rr < MK; rr++) {
      float fct = A[rr][c] * inv;
#pragma unroll
      for (int cc = c; cc < MK; cc++) A[rr][cc] -= fct * A[c][cc];
      bv[rr] -= fct * bv[c];
    }
  }
#pragma unroll
  for (int i = MK - 1; i >= 0; i--) {
    float s = bv[i];
#pragma unroll
    for (int j = i + 1; j < MK; j++) s -= A[i][j] * alpha[j];
    alpha[i] = s / A[i][i];
  }

  f32x2 x = Fm1;
#pragma unroll
  for (int i = 0; i < MK; i++) x -= dF[i] * alpha[i];
  *(f32x2*)(Xw + base) = x;
  if (zc != nullptr) {
    union { __hip_bfloat16 h[2]; unsigned int u; } cv;
    cv.h[0] = __float2bfloat16(x[0]);
    cv.h[1] = __float2bfloat16(x[1]);
    *(unsigned int*)(zc + (size_t)b * KCAT + half * 128 + 2 * lane) = cv.u;
  }
}

// ---------------- host orchestration ---------------------------------------
static void eval_f(const __hip_bfloat16* zc, const __hip_bfloat16* W1b,
                   const __hip_bfloat16* W2b, const float* b1, const float* b2,
                   __hip_bfloat16* hb, float* Fout, hipStream_t stream) {
  gemm_mfma<64, 64, true><<<dim3(B_ROWS / 64, D_HID / 64), 256, 0, stream>>>(
      zc, W1b, KCAT, b1, nullptr, hb, D_HID);
  gemm_mfma<32, 32, false><<<dim3(B_ROWS / 32, D_LAT / 32), 256, 0, stream>>>(
      hb, W2b, D_HID, b2, Fout, nullptr, D_LAT);
}

extern "C" void kernel_launch(void* const* d_in, const int* in_sizes, int n_in,
                              void* d_out, int out_size, void* d_ws,
                              size_t ws_size, hipStream_t stream) {
  const float* ctx = (const float*)d_in[0];
  const float* W1 = (const float*)d_in[1];
  const float* b1 = (const float*)d_in[2];
  const float* W2 = (const float*)d_in[3];
  const float* b2 = (const float*)d_in[4];
  float* out = (float*)d_out;

  float* ws = (float*)d_ws;
  float* sig = ws;                       // 16
  float* vA = ws + 16;                   // 512
  float* vB = vA + KCAT;                 // 512
  float* uA = vB + KCAT;                 // 256
  float* uB = uA + D_LAT;                // 256
  float* G1p = uB + D_LAT;               // 512*512
  float* G2 = G1p + KCAT * KCAT;         // 256*256
  float* Xh = G2 + D_LAT * D_LAT;        // 7*SLOT
  float* Fh = Xh + NRING * SLOT;         // 7*SLOT
  __hip_bfloat16* W1b = (__hip_bfloat16*)(Fh + NRING * SLOT);  // 524288
  __hip_bfloat16* W2b = W1b + D_HID * KCAT;                    // 262144
  __hip_bfloat16* zc = W2b + D_LAT * D_HID;                    // 2048*512
  __hip_bfloat16* hb = zc + B_ROWS * KCAT;                     // 2048*1024
  // ~38.5 MB total

  init_kernel<<<(B_ROWS * KCAT + 255) / 256, 256, 0, stream>>>(ctx, zc, vA, uA,
                                                               G1p, G2);
  // Gram (1024 + 256) + colsum (64)
  gram_kernel<<<1344, 256, 0, stream>>>(W1, W2, G1p, G2, vA);

  for (int it = 1; it <= 21; it++) {
    const float* vi; float* vo;
    const float* ui; float* uo;
    if (it & 1) { vi = vB; vo = vA; ui = uA; uo = uB; }
    else        { vi = vA; vo = vB; ui = uB; uo = uA; }
    pmv_kernel<<<192, 256, 0, stream>>>(G1p, G2, vi, vo, ui, uo, it >= 2);
  }
  sigma_kernel<<<1, 256, 0, stream>>>(vA, vB, uA, uB, sig);
  wfold_kernel<<<(D_HID * KCAT + D_LAT * D_HID + 255) / 256, 256, 0, stream>>>(
      W1, W2, sig, W1b, W2b);

  hipMemsetAsync(Xh, 0, SLOT * sizeof(float), stream);

  eval_f(zc, W1b, W2b, b1, b2, hb, Fh, stream);
  warm1_kernel<<<SLOT / 256, 256, 0, stream>>>(Fh, Xh, zc);
  eval_f(zc, W1b, W2b, b1, b2, hb, Fh + SLOT, stream);
  warm2_kernel<<<SLOT / 256, 256, 0, stream>>>(Fh, Xh, Fh);

  // Anderson loop: t = 3..25
  for (int t = 3; t <= 25; t++) {
    int mk = (t - 1 < 5) ? (t - 1) : 5;
    float* Xw = (t == 25) ? out : (Xh + (t % NRING) * SLOT);
    __hip_bfloat16* zarg = (t == 25) ? nullptr : zc;
    dim3 g(B_ROWS / 2);
    if (mk == 2)
      anderson_step_kernel<2><<<g, 256, 0, stream>>>(Xh, Fh, Xw, zarg, t);
    else if (mk == 3)
      anderson_step_kernel<3><<<g, 256, 0, stream>>>(Xh, Fh, Xw, zarg, t);
    else if (mk == 4)
      anderson_step_kernel<4><<<g, 256, 0, stream>>>(Xh, Fh, Xw, zarg, t);
    else
      anderson_step_kernel<5><<<g, 256, 0, stream>>>(Xh, Fh, Xw, zarg, t);
    if (t < 25) {
      eval_f(zc, W1b, W2b, b1, b2, hb, Fh + (t % NRING) * SLOT, stream);
    }
  }
}

// Round 7
// 820.097 us; speedup vs baseline: 1.2151x; 1.0658x over previous
//
#include <hip/hip_runtime.h>
#include <hip/hip_bf16.h>

// ---------------------------------------------------------------------------
// DEQ layer, MI355X round 11.
//  - Full revert to round-8 structure (verified 813us): gram 64x32 tiles
//    (1280 blk) + separate colsum; 21-launch pmv chain; gemm1 64x64 /
//    gemm2 32x32; anderson v2 wave-per-row.
//  - anderson v2.1 (only change): f32 solve (validated same absmax in R9/
//    R10; f64 is half-rate + slow divides, ~70 VGPR heavier) and explicit
//    batched history loads (12 independent f32x4 loads before any
//    differencing -> full MLP for L3 latency).
//  - Lessons: R9 fusion (VGPR cap spill + 128-blk grid) and R10 2-wave-row
//    (2x shuffle work + LDS sync) both regressed; v2 is instruction/latency
//    bound, not TLP-bound.
// ---------------------------------------------------------------------------

#define B_ROWS 2048
#define D_LAT  256
#define D_CTX  256
#define D_HID  1024
#define KCAT   512
#define SLOT   (B_ROWS * D_LAT)
#define NRING  7

typedef __bf16 bf16x8 __attribute__((ext_vector_type(8)));
typedef float f32x4 __attribute__((ext_vector_type(4)));
typedef unsigned short u16;

// ---------------- init: zc = [bf16(0)|bf16(ctx)], uA=1, vA=0, G=0 ----------
__global__ void init_kernel(const float* __restrict__ ctx,
                            __hip_bfloat16* __restrict__ zc,
                            float* __restrict__ vA, float* __restrict__ uA,
                            float* __restrict__ G1p, float* __restrict__ G2) {
  int i = blockIdx.x * 256 + threadIdx.x;
  if (i < B_ROWS * KCAT) {
    int b = i >> 9, c = i & 511;
    float v = (c < 256) ? 0.0f : ctx[b * 256 + (c - 256)];
    zc[i] = __float2bfloat16(v);
  }
  if (i < 512 * 512) G1p[i] = 0.0f;
  if (i < 256 * 256) G2[i] = 0.0f;
  if (i < KCAT) vA[i] = 0.0f;
  if (i < D_LAT) uA[i] = 1.0f;
}

// ---------------- Gram build, split-K x8, 64x32 tiles, atomic accum --------
// blocks 0..1023:  G1' = W1^T W1 (mode A: G[i][j] = sum_k X[k*512+i]X[k*512+j])
// blocks 1024..1279: G2 = W2 W2^T (mode B: G[i][j]=sum_k X[i*1024+k]X[j*1024+k])
__global__ __launch_bounds__(256) void gram_kernel(
    const float* __restrict__ W1, const float* __restrict__ W2,
    float* __restrict__ G1p, float* __restrict__ G2) {
  __shared__ float As[32][66];
  __shared__ float Bs[32][34];
  const int tid = threadIdx.x;
  const int tx = tid & 15, ty = tid >> 4;

  const float* X; float* G; int N, ti, tj, k0base; bool modeA;
  int b = blockIdx.x;
  if (b < 1024) {
    modeA = true; X = W1; G = G1p; N = 512;
    int s = b >> 7, t = b & 127;
    ti = t >> 4; tj = t & 15; k0base = s * 128;
  } else {
    modeA = false; b -= 1024; X = W2; G = G2; N = 256;
    int s = b >> 5, t = b & 31;
    ti = t >> 3; tj = t & 7; k0base = s * 128;
  }

  float acc[4][2] = {};
  for (int k0 = k0base; k0 < k0base + 128; k0 += 32) {
    if (modeA) {
      for (int idx = tid; idx < 2048; idx += 256) {
        int r = idx & 63, c = idx >> 6;
        As[c][r] = X[(size_t)(k0 + c) * 512 + ti * 64 + r];
      }
      for (int idx = tid; idx < 1024; idx += 256) {
        int r = idx & 31, c = idx >> 5;
        Bs[c][r] = X[(size_t)(k0 + c) * 512 + tj * 32 + r];
      }
    } else {
      for (int idx = tid; idx < 2048; idx += 256) {
        int c = idx & 31, r = idx >> 5;
        As[c][r] = X[(size_t)(ti * 64 + r) * 1024 + k0 + c];
      }
      for (int idx = tid; idx < 1024; idx += 256) {
        int c = idx & 31, r = idx >> 5;
        Bs[c][r] = X[(size_t)(tj * 32 + r) * 1024 + k0 + c];
      }
    }
    __syncthreads();
#pragma unroll
    for (int kk = 0; kk < 32; kk++) {
      const float2* ap = (const float2*)&As[kk][ty * 4];
      float2 a0 = ap[0], a1 = ap[1];
      float2 b0 = *(const float2*)&Bs[kk][tx * 2];
      float a[4] = {a0.x, a0.y, a1.x, a1.y};
      float bb[2] = {b0.x, b0.y};
#pragma unroll
      for (int i = 0; i < 4; i++)
#pragma unroll
        for (int j = 0; j < 2; j++) acc[i][j] += a[i] * bb[j];
    }
    __syncthreads();
  }
#pragma unroll
  for (int i = 0; i < 4; i++)
#pragma unroll
    for (int j = 0; j < 2; j++)
      atomicAdd(&G[(size_t)(ti * 64 + ty * 4 + i) * N + tj * 32 + tx * 2 + j],
                acc[i][j]);
}

// ---------------- colsum: vA += W1^T ones (atomic partials) ----------------
__global__ __launch_bounds__(256) void colsum_kernel(
    const float* __restrict__ W1, float* __restrict__ vA) {
  int b = blockIdx.x;  // 64 blocks, rows [16b,16b+16)
  for (int c = threadIdx.x; c < KCAT; c += 256) {
    float s = 0.f;
#pragma unroll
    for (int r = 0; r < 16; r++) s += W1[(size_t)(16 * b + r) * KCAT + c];
    atomicAdd(&vA[c], s);
  }
}

// ---------------- joint power matvec: out = 0.25 * G in --------------------
__global__ __launch_bounds__(256) void pmv_kernel(
    const float* __restrict__ G1p, const float* __restrict__ G2,
    const float* __restrict__ vi, float* __restrict__ vo,
    const float* __restrict__ ui, float* __restrict__ uo, int g1_active) {
  int gw = blockIdx.x * 4 + (threadIdx.x >> 6);
  int lane = threadIdx.x & 63;
  const float* G; const float* in; float* out; int n, r;
  if (gw < 512) {
    if (!g1_active) return;
    G = G1p; in = vi; out = vo; n = 512; r = gw;
  } else {
    G = G2; in = ui; out = uo; n = 256; r = gw - 512;
  }
  const float4* Gr = (const float4*)(G + (size_t)r * n);
  const float4* uv = (const float4*)in;
  float acc = 0.f;
  for (int c = lane; c < (n >> 2); c += 64) {
    float4 g = Gr[c], u = uv[c];
    acc += g.x * u.x + g.y * u.y + g.z * u.z + g.w * u.w;
  }
  for (int off = 32; off; off >>= 1) acc += __shfl_down(acc, off, 64);
  if (lane == 0) out[r] = 0.25f * acc;
}

// ---------------- sigma ----------------------------------------------------
__global__ __launch_bounds__(256) void sigma_kernel(
    const float* __restrict__ vA, const float* __restrict__ vB,
    const float* __restrict__ uA, const float* __restrict__ uB,
    float* __restrict__ sig) {
  float s[4] = {0.f, 0.f, 0.f, 0.f};
  for (int i = threadIdx.x; i < KCAT; i += 256) {
    s[0] += vA[i] * vB[i];
    s[1] += vA[i] * vA[i];
  }
  for (int i = threadIdx.x; i < D_LAT; i += 256) {
    s[2] += uA[i] * uA[i];
    s[3] += uA[i] * uB[i];
  }
  __shared__ float red[4][4];
  int lane = threadIdx.x & 63, w = threadIdx.x >> 6;
  for (int k = 0; k < 4; k++) {
    float a = s[k];
    for (int off = 32; off; off >>= 1) a += __shfl_down(a, off, 64);
    if (lane == 0) red[k][w] = a;
  }
  __syncthreads();
  if (threadIdx.x == 0) {
    float d0 = red[0][0] + red[0][1] + red[0][2] + red[0][3];
    float d1 = red[1][0] + red[1][1] + red[1][2] + red[1][3];
    float d2 = red[2][0] + red[2][1] + red[2][2] + red[2][3];
    float d3 = red[3][0] + red[3][1] + red[3][2] + red[3][3];
    sig[0] = sqrtf(0.25f * d0 / d1);
    sig[1] = sqrtf(0.25f * d2 / d3);
  }
}

// ---------------- fold sigma into bf16 weights -----------------------------
__global__ void wfold_kernel(const float* __restrict__ W1,
                             const float* __restrict__ W2,
                             const float* __restrict__ sig,
                             __hip_bfloat16* __restrict__ W1b,
                             __hip_bfloat16* __restrict__ W2b) {
  int i = blockIdx.x * 256 + threadIdx.x;
  if (i < D_HID * KCAT) W1b[i] = __float2bfloat16(W1[i] * sig[0]);
  int j = i - D_HID * KCAT;
  if (j >= 0 && j < D_LAT * D_HID) W2b[j] = __float2bfloat16(W2[j] * sig[1]);
}

// ---------------- warm-up fusions ------------------------------------------
__global__ void warm1_kernel(const float* __restrict__ Fh,
                             float* __restrict__ Xh,
                             __hip_bfloat16* __restrict__ zc) {
  int i = blockIdx.x * 256 + threadIdx.x;
  float v = Fh[i];
  Xh[SLOT + i] = v;
  zc[(i >> 8) * KCAT + (i & 255)] = __float2bfloat16(v);
}
__global__ void warm2_kernel(const float* __restrict__ Fh,
                             float* __restrict__ Xh, float* __restrict__ Fw) {
  int i = blockIdx.x * 256 + threadIdx.x;
  Xh[2 * SLOT + i] = Fh[i];
  Fw[2 * SLOT + i] = Fh[SLOT + i];
}

// ---------------- bf16 MFMA GEMM: C = tanh(A @ W^T + bias) -----------------
template <int BM, int BN, bool OUT_BF16>
__global__ __launch_bounds__(256) void gemm_mfma(
    const __hip_bfloat16* __restrict__ A, const __hip_bfloat16* __restrict__ W,
    int K, const float* __restrict__ bias, float* __restrict__ Cf,
    __hip_bfloat16* __restrict__ Cb, int N) {
  __shared__ __align__(16) u16 lds[(BM + BN) * 64];
  u16* As = lds;
  u16* Ws = lds + BM * 64;
  const int tid = threadIdx.x;
  const int lane = tid & 63;
  const int wid = tid >> 6;
  const int wy = wid >> 1, wx = wid & 1;
  constexpr int WM = BM / 2, WN = BN / 2;
  constexpr int MB = WM / 16, NB = WN / 16;
  const int bm = blockIdx.x * BM;
  const int bn = blockIdx.y * BN;
  const int rlo = lane & 15, quad = lane >> 4;

  f32x4 acc[MB][NB] = {};

  for (int k0 = 0; k0 < K; k0 += 64) {
    for (int c = tid; c < BM * 8; c += 256) {
      int r = c >> 3, o = (c & 7) ^ (r & 7);
      __builtin_amdgcn_global_load_lds(
          (const __attribute__((address_space(1))) void*)(A + (size_t)(bm + r) * K + k0 + o * 8),
          (__attribute__((address_space(3))) void*)(As + c * 8), 16, 0, 0);
    }
    for (int c = tid; c < BN * 8; c += 256) {
      int r = c >> 3, o = (c & 7) ^ (r & 7);
      __builtin_amdgcn_global_load_lds(
          (const __attribute__((address_space(1))) void*)(W + (size_t)(bn + r) * K + k0 + o * 8),
          (__attribute__((address_space(3))) void*)(Ws + c * 8), 16, 0, 0);
    }
    __syncthreads();
#pragma unroll
    for (int kk = 0; kk < 2; kk++) {
      bf16x8 af[MB], bfr[NB];
#pragma unroll
      for (int mb = 0; mb < MB; mb++) {
        int r = wy * WM + mb * 16 + rlo;
        int o = (kk * 4 + quad) ^ (r & 7);
        af[mb] = *(const bf16x8*)(As + (r * 8 + o) * 8);
      }
#pragma unroll
      for (int nb = 0; nb < NB; nb++) {
        int r = wx * WN + nb * 16 + rlo;
        int o = (kk * 4 + quad) ^ (r & 7);
        bfr[nb] = *(const bf16x8*)(Ws + (r * 8 + o) * 8);
      }
#pragma unroll
      for (int mb = 0; mb < MB; mb++)
#pragma unroll
        for (int nb = 0; nb < NB; nb++)
          acc[mb][nb] = __builtin_amdgcn_mfma_f32_16x16x32_bf16(
              af[mb], bfr[nb], acc[mb][nb], 0, 0, 0);
    }
    __syncthreads();
  }

#pragma unroll
  for (int mb = 0; mb < MB; mb++) {
#pragma unroll
    for (int nb = 0; nb < NB; nb++) {
      int n = bn + wx * WN + nb * 16 + rlo;
      float bv = bias[n];
#pragma unroll
      for (int rg = 0; rg < 4; rg++) {
        int m = bm + wy * WM + mb * 16 + quad * 4 + rg;
        float val = tanhf(acc[mb][nb][rg] + bv);
        if constexpr (OUT_BF16) {
          Cb[(size_t)m * N + n] = __float2bfloat16(val);
        } else {
          Cf[(size_t)m * N + n] = val;
        }
      }
    }
  }
}

// ---------------- Anderson step v2.1 (wave per row, reg-resident) ----------
// Changes vs v2: all 2(MK+1) history slots loaded into independent regs
// BEFORE differencing (full load-level parallelism), and f32 solve
// (validated R9/R10: same absmax; f64 is half-rate + slow divides).
template <int MK>
__global__ __launch_bounds__(256) void anderson_step_kernel(
    const float* __restrict__ Xh, const float* __restrict__ Fh,
    float* __restrict__ Xw, __hip_bfloat16* __restrict__ zc, int t) {
  const int lane = threadIdx.x & 63;
  const int wid = threadIdx.x >> 6;
  const int b = blockIdx.x * 4 + wid;
  const int base = b * D_LAT + 4 * lane;

  // batched loads: 2*(MK+1) independent f32x4 loads
  f32x4 f[MK + 1], x[MK + 1];
#pragma unroll
  for (int i = 0; i <= MK; i++) {
    int sl = (t - 1 - i) % NRING;
    f[i] = *(const f32x4*)(Fh + (size_t)sl * SLOT + base);
    x[i] = *(const f32x4*)(Xh + (size_t)sl * SLOT + base);
  }

  const f32x4 r = f[0] - x[0];
  f32x4 dF[MK], dG[MK];
#pragma unroll
  for (int i = 0; i < MK; i++) {
    dF[i] = f[i] - f[i + 1];
    dG[i] = dF[i] - (x[i] - x[i + 1]);
  }

  constexpr int NV = MK * (MK + 1) / 2 + MK;
  float vals[NV];
  {
    int p = 0;
#pragma unroll
    for (int i = 0; i < MK; i++)
#pragma unroll
      for (int j = i; j < MK; j++) {
        f32x4 q = dG[i] * dG[j];
        vals[p++] = q[0] + q[1] + q[2] + q[3];
      }
#pragma unroll
    for (int i = 0; i < MK; i++) {
      f32x4 q = dG[i] * r;
      vals[p++] = q[0] + q[1] + q[2] + q[3];
    }
  }
#pragma unroll
  for (int off = 1; off <= 32; off <<= 1)
#pragma unroll
    for (int v = 0; v < NV; v++) vals[v] += __shfl_xor(vals[v], off, 64);

  float A[MK][MK], bv[MK], alpha[MK];
  {
    int p = 0;
#pragma unroll
    for (int i = 0; i < MK; i++)
#pragma unroll
      for (int j = i; j < MK; j++) {
        A[i][j] = vals[p];
        A[j][i] = vals[p];
        p++;
      }
#pragma unroll
    for (int i = 0; i < MK; i++) A[i][i] += 1e-4f;
#pragma unroll
    for (int i = 0; i < MK; i++) bv[i] = vals[p++];
  }

#pragma unroll
  for (int c = 0; c < MK; c++) {
    float inv = 1.0f / A[c][c];
#pragma unroll
    for (int rr = c + 1; rr < MK; rr++) {
      float fct = A[rr][c] * inv;
#pragma unroll
      for (int cc = c; cc < MK; cc++) A[rr][cc] -= fct * A[c][cc];
      bv[rr] -= fct * bv[c];
    }
  }
#pragma unroll
  for (int i = MK - 1; i >= 0; i--) {
    float s = bv[i];
#pragma unroll
    for (int j = i + 1; j < MK; j++) s -= A[i][j] * alpha[j];
    alpha[i] = s / A[i][i];
  }

  f32x4 xo = f[0];
#pragma unroll
  for (int i = 0; i < MK; i++) xo -= dF[i] * alpha[i];
  *(f32x4*)(Xw + base) = xo;
  if (zc != nullptr) {
    union { __hip_bfloat16 h[4]; unsigned long long u; } cv;
#pragma unroll
    for (int j = 0; j < 4; j++) cv.h[j] = __float2bfloat16(xo[j]);
    *(unsigned long long*)(zc + (size_t)b * KCAT + 4 * lane) = cv.u;
  }
}

// ---------------- host orchestration ---------------------------------------
static void eval_f(const __hip_bfloat16* zc, const __hip_bfloat16* W1b,
                   const __hip_bfloat16* W2b, const float* b1, const float* b2,
                   __hip_bfloat16* hb, float* Fout, hipStream_t stream) {
  gemm_mfma<64, 64, true><<<dim3(B_ROWS / 64, D_HID / 64), 256, 0, stream>>>(
      zc, W1b, KCAT, b1, nullptr, hb, D_HID);
  gemm_mfma<32, 32, false><<<dim3(B_ROWS / 32, D_LAT / 32), 256, 0, stream>>>(
      hb, W2b, D_HID, b2, Fout, nullptr, D_LAT);
}

extern "C" void kernel_launch(void* const* d_in, const int* in_sizes, int n_in,
                              void* d_out, int out_size, void* d_ws,
                              size_t ws_size, hipStream_t stream) {
  const float* ctx = (const float*)d_in[0];
  const float* W1 = (const float*)d_in[1];
  const float* b1 = (const float*)d_in[2];
  const float* W2 = (const float*)d_in[3];
  const float* b2 = (const float*)d_in[4];
  float* out = (float*)d_out;

  float* ws = (float*)d_ws;
  float* sig = ws;                       // 16
  float* vA = ws + 16;                   // 512
  float* vB = vA + KCAT;                 // 512
  float* uA = vB + KCAT;                 // 256
  float* uB = uA + D_LAT;                // 256
  float* G1p = uB + D_LAT;               // 512*512
  float* G2 = G1p + KCAT * KCAT;         // 256*256
  float* Xh = G2 + D_LAT * D_LAT;        // 7*SLOT
  float* Fh = Xh + NRING * SLOT;         // 7*SLOT
  __hip_bfloat16* W1b = (__hip_bfloat16*)(Fh + NRING * SLOT);  // 524288
  __hip_bfloat16* W2b = W1b + D_HID * KCAT;                    // 262144
  __hip_bfloat16* zc = W2b + D_LAT * D_HID;                    // 2048*512
  __hip_bfloat16* hb = zc + B_ROWS * KCAT;                     // 2048*1024
  // ~38.5 MB total

  init_kernel<<<(B_ROWS * KCAT + 255) / 256, 256, 0, stream>>>(ctx, zc, vA, uA,
                                                               G1p, G2);
  gram_kernel<<<1280, 256, 0, stream>>>(W1, W2, G1p, G2);
  colsum_kernel<<<64, 256, 0, stream>>>(W1, vA);

  for (int it = 1; it <= 21; it++) {
    const float* vi; float* vo;
    const float* ui; float* uo;
    if (it & 1) { vi = vB; vo = vA; ui = uA; uo = uB; }
    else        { vi = vA; vo = vB; ui = uB; uo = uA; }
    pmv_kernel<<<192, 256, 0, stream>>>(G1p, G2, vi, vo, ui, uo, it >= 2);
  }
  sigma_kernel<<<1, 256, 0, stream>>>(vA, vB, uA, uB, sig);
  wfold_kernel<<<(D_HID * KCAT + D_LAT * D_HID + 255) / 256, 256, 0, stream>>>(
      W1, W2, sig, W1b, W2b);

  hipMemsetAsync(Xh, 0, SLOT * sizeof(float), stream);

  eval_f(zc, W1b, W2b, b1, b2, hb, Fh, stream);
  warm1_kernel<<<SLOT / 256, 256, 0, stream>>>(Fh, Xh, zc);
  eval_f(zc, W1b, W2b, b1, b2, hb, Fh + SLOT, stream);
  warm2_kernel<<<SLOT / 256, 256, 0, stream>>>(Fh, Xh, Fh);

  // Anderson loop: t = 3..25
  for (int t = 3; t <= 25; t++) {
    int mk = (t - 1 < 5) ? (t - 1) : 5;
    float* Xw = (t == 25) ? out : (Xh + (t % NRING) * SLOT);
    __hip_bfloat16* zarg = (t == 25) ? nullptr : zc;
    dim3 g(B_ROWS / 4);
    if (mk == 2)
      anderson_step_kernel<2><<<g, 256, 0, stream>>>(Xh, Fh, Xw, zarg, t);
    else if (mk == 3)
      anderson_step_kernel<3><<<g, 256, 0, stream>>>(Xh, Fh, Xw, zarg, t);
    else if (mk == 4)
      anderson_step_kernel<4><<<g, 256, 0, stream>>>(Xh, Fh, Xw, zarg, t);
    else
      anderson_step_kernel<5><<<g, 256, 0, stream>>>(Xh, Fh, Xw, zarg, t);
    if (t < 25) {
      eval_f(zc, W1b, W2b, b1, b2, hb, Fh + (t % NRING) * SLOT, stream);
    }
  }
}

// Round 8
// 815.053 us; speedup vs baseline: 1.2227x; 1.0062x over previous
//
#include <hip/hip_runtime.h>
#include <hip/hip_bf16.h>

// ---------------------------------------------------------------------------
// DEQ layer, MI355X round 12.
//  - GEMMs: 2-phase double-buffered LDS (T3 minimal recipe, safe variant):
//    STAGE(next buf) issued BEFORE compute(cur), ONE __syncthreads per
//    K-step (was 2 + full drain before compute). K templated -> static
//    unroll. Accumulation order per output unchanged (bit-identical F).
//  - pmv chain: operator squaring. H1=G1p^2, H2=G2^2 built once (gsq,
//    symmetric-G gram pattern, direct stores); chain = 1 G-step (u) +
//    9 joint H-steps (scale 0.0625 = two damped steps) + 2 exact G-steps
//    = 12 launches (was 21). Launch-overhead bound -> ~-25us.
//  - anderson v2.1 (f32, wave/row): declared at latency floor (~15us);
//    3 structural attempts failed; unchanged.
//  - gram 64x32 (1280 blk) + colsum: unchanged (round-8 verified).
// ---------------------------------------------------------------------------

#define B_ROWS 2048
#define D_LAT  256
#define D_CTX  256
#define D_HID  1024
#define KCAT   512
#define SLOT   (B_ROWS * D_LAT)
#define NRING  7

typedef __bf16 bf16x8 __attribute__((ext_vector_type(8)));
typedef float f32x4 __attribute__((ext_vector_type(4)));
typedef unsigned short u16;

// ---------------- init: zc = [bf16(0)|bf16(ctx)], uA=1, vA=0, G=0 ----------
__global__ void init_kernel(const float* __restrict__ ctx,
                            __hip_bfloat16* __restrict__ zc,
                            float* __restrict__ vA, float* __restrict__ uA,
                            float* __restrict__ G1p, float* __restrict__ G2) {
  int i = blockIdx.x * 256 + threadIdx.x;
  if (i < B_ROWS * KCAT) {
    int b = i >> 9, c = i & 511;
    float v = (c < 256) ? 0.0f : ctx[b * 256 + (c - 256)];
    zc[i] = __float2bfloat16(v);
  }
  if (i < 512 * 512) G1p[i] = 0.0f;
  if (i < 256 * 256) G2[i] = 0.0f;
  if (i < KCAT) vA[i] = 0.0f;
  if (i < D_LAT) uA[i] = 1.0f;
}

// ---------------- Gram build, split-K x8, 64x32 tiles, atomic accum --------
__global__ __launch_bounds__(256) void gram_kernel(
    const float* __restrict__ W1, const float* __restrict__ W2,
    float* __restrict__ G1p, float* __restrict__ G2) {
  __shared__ float As[32][66];
  __shared__ float Bs[32][34];
  const int tid = threadIdx.x;
  const int tx = tid & 15, ty = tid >> 4;

  const float* X; float* G; int N, ti, tj, k0base; bool modeA;
  int b = blockIdx.x;
  if (b < 1024) {
    modeA = true; X = W1; G = G1p; N = 512;
    int s = b >> 7, t = b & 127;
    ti = t >> 4; tj = t & 15; k0base = s * 128;
  } else {
    modeA = false; b -= 1024; X = W2; G = G2; N = 256;
    int s = b >> 5, t = b & 31;
    ti = t >> 3; tj = t & 7; k0base = s * 128;
  }

  float acc[4][2] = {};
  for (int k0 = k0base; k0 < k0base + 128; k0 += 32) {
    if (modeA) {
      for (int idx = tid; idx < 2048; idx += 256) {
        int r = idx & 63, c = idx >> 6;
        As[c][r] = X[(size_t)(k0 + c) * 512 + ti * 64 + r];
      }
      for (int idx = tid; idx < 1024; idx += 256) {
        int r = idx & 31, c = idx >> 5;
        Bs[c][r] = X[(size_t)(k0 + c) * 512 + tj * 32 + r];
      }
    } else {
      for (int idx = tid; idx < 2048; idx += 256) {
        int c = idx & 31, r = idx >> 5;
        As[c][r] = X[(size_t)(ti * 64 + r) * 1024 + k0 + c];
      }
      for (int idx = tid; idx < 1024; idx += 256) {
        int c = idx & 31, r = idx >> 5;
        Bs[c][r] = X[(size_t)(tj * 32 + r) * 1024 + k0 + c];
      }
    }
    __syncthreads();
#pragma unroll
    for (int kk = 0; kk < 32; kk++) {
      const float2* ap = (const float2*)&As[kk][ty * 4];
      float2 a0 = ap[0], a1 = ap[1];
      float2 b0 = *(const float2*)&Bs[kk][tx * 2];
      float a[4] = {a0.x, a0.y, a1.x, a1.y};
      float bb[2] = {b0.x, b0.y};
#pragma unroll
      for (int i = 0; i < 4; i++)
#pragma unroll
        for (int j = 0; j < 2; j++) acc[i][j] += a[i] * bb[j];
    }
    __syncthreads();
  }
#pragma unroll
  for (int i = 0; i < 4; i++)
#pragma unroll
    for (int j = 0; j < 2; j++)
      atomicAdd(&G[(size_t)(ti * 64 + ty * 4 + i) * N + tj * 32 + tx * 2 + j],
                acc[i][j]);
}

// ---------------- colsum: vA += W1^T ones (atomic partials) ----------------
__global__ __launch_bounds__(256) void colsum_kernel(
    const float* __restrict__ W1, float* __restrict__ vA) {
  int b = blockIdx.x;
  for (int c = threadIdx.x; c < KCAT; c += 256) {
    float s = 0.f;
#pragma unroll
    for (int r = 0; r < 16; r++) s += W1[(size_t)(16 * b + r) * KCAT + c];
    atomicAdd(&vA[c], s);
  }
}

// ---------------- H = G^2 (G symmetric): gram-mode-B pattern, direct store -
// blocks 0..127: H1 = G1p.G1p^T (8x16 tiles 64x32, K=512)
// blocks 128..159: H2 = G2.G2^T (4x8 tiles, K=256)
__global__ __launch_bounds__(256) void gsq_kernel(
    const float* __restrict__ G1p, const float* __restrict__ G2,
    float* __restrict__ H1, float* __restrict__ H2) {
  __shared__ float As[32][66];
  __shared__ float Bs[32][34];
  const int tid = threadIdx.x;
  const int tx = tid & 15, ty = tid >> 4;
  const float* X; float* H; int N, ti, tj;
  int b = blockIdx.x;
  if (b < 128) { X = G1p; H = H1; N = 512; ti = b >> 4; tj = b & 15; }
  else { b -= 128; X = G2; H = H2; N = 256; ti = b >> 3; tj = b & 7; }

  float acc[4][2] = {};
  for (int k0 = 0; k0 < N; k0 += 32) {
    for (int idx = tid; idx < 2048; idx += 256) {
      int c = idx & 31, r = idx >> 5;
      As[c][r] = X[(size_t)(ti * 64 + r) * N + k0 + c];
    }
    for (int idx = tid; idx < 1024; idx += 256) {
      int c = idx & 31, r = idx >> 5;
      Bs[c][r] = X[(size_t)(tj * 32 + r) * N + k0 + c];
    }
    __syncthreads();
#pragma unroll
    for (int kk = 0; kk < 32; kk++) {
      const float2* ap = (const float2*)&As[kk][ty * 4];
      float2 a0 = ap[0], a1 = ap[1];
      float2 b0 = *(const float2*)&Bs[kk][tx * 2];
      float a[4] = {a0.x, a0.y, a1.x, a1.y};
      float bb[2] = {b0.x, b0.y};
#pragma unroll
      for (int i = 0; i < 4; i++)
#pragma unroll
        for (int j = 0; j < 2; j++) acc[i][j] += a[i] * bb[j];
    }
    __syncthreads();
  }
#pragma unroll
  for (int i = 0; i < 4; i++)
#pragma unroll
    for (int j = 0; j < 2; j++)
      H[(size_t)(ti * 64 + ty * 4 + i) * N + tj * 32 + tx * 2 + j] = acc[i][j];
}

// ---------------- joint power matvec: out = scale * M in -------------------
__global__ __launch_bounds__(256) void pmv_kernel(
    const float* __restrict__ Mv, const float* __restrict__ Mu,
    const float* __restrict__ vi, float* __restrict__ vo,
    const float* __restrict__ ui, float* __restrict__ uo,
    float scale, int v_active) {
  int gw = blockIdx.x * 4 + (threadIdx.x >> 6);
  int lane = threadIdx.x & 63;
  const float* M; const float* in; float* out; int n, r;
  if (gw < 512) {
    if (!v_active) return;
    M = Mv; in = vi; out = vo; n = 512; r = gw;
  } else {
    M = Mu; in = ui; out = uo; n = 256; r = gw - 512;
  }
  const float4* Mr = (const float4*)(M + (size_t)r * n);
  const float4* uv = (const float4*)in;
  float acc = 0.f;
  for (int c = lane; c < (n >> 2); c += 64) {
    float4 g = Mr[c], u = uv[c];
    acc += g.x * u.x + g.y * u.y + g.z * u.z + g.w * u.w;
  }
  for (int off = 32; off; off >>= 1) acc += __shfl_down(acc, off, 64);
  if (lane == 0) out[r] = scale * acc;
}

// ---------------- sigma ----------------------------------------------------
// args: (v21, v20, u20, u21)
__global__ __launch_bounds__(256) void sigma_kernel(
    const float* __restrict__ vA, const float* __restrict__ vB,
    const float* __restrict__ uA, const float* __restrict__ uB,
    float* __restrict__ sig) {
  float s[4] = {0.f, 0.f, 0.f, 0.f};
  for (int i = threadIdx.x; i < KCAT; i += 256) {
    s[0] += vA[i] * vB[i];
    s[1] += vA[i] * vA[i];
  }
  for (int i = threadIdx.x; i < D_LAT; i += 256) {
    s[2] += uA[i] * uA[i];
    s[3] += uA[i] * uB[i];
  }
  __shared__ float red[4][4];
  int lane = threadIdx.x & 63, w = threadIdx.x >> 6;
  for (int k = 0; k < 4; k++) {
    float a = s[k];
    for (int off = 32; off; off >>= 1) a += __shfl_down(a, off, 64);
    if (lane == 0) red[k][w] = a;
  }
  __syncthreads();
  if (threadIdx.x == 0) {
    float d0 = red[0][0] + red[0][1] + red[0][2] + red[0][3];
    float d1 = red[1][0] + red[1][1] + red[1][2] + red[1][3];
    float d2 = red[2][0] + red[2][1] + red[2][2] + red[2][3];
    float d3 = red[3][0] + red[3][1] + red[3][2] + red[3][3];
    sig[0] = sqrtf(0.25f * d0 / d1);
    sig[1] = sqrtf(0.25f * d2 / d3);
  }
}

// ---------------- fold sigma into bf16 weights -----------------------------
__global__ void wfold_kernel(const float* __restrict__ W1,
                             const float* __restrict__ W2,
                             const float* __restrict__ sig,
                             __hip_bfloat16* __restrict__ W1b,
                             __hip_bfloat16* __restrict__ W2b) {
  int i = blockIdx.x * 256 + threadIdx.x;
  if (i < D_HID * KCAT) W1b[i] = __float2bfloat16(W1[i] * sig[0]);
  int j = i - D_HID * KCAT;
  if (j >= 0 && j < D_LAT * D_HID) W2b[j] = __float2bfloat16(W2[j] * sig[1]);
}

// ---------------- warm-up fusions ------------------------------------------
__global__ void warm1_kernel(const float* __restrict__ Fh,
                             float* __restrict__ Xh,
                             __hip_bfloat16* __restrict__ zc) {
  int i = blockIdx.x * 256 + threadIdx.x;
  float v = Fh[i];
  Xh[SLOT + i] = v;
  zc[(i >> 8) * KCAT + (i & 255)] = __float2bfloat16(v);
}
__global__ void warm2_kernel(const float* __restrict__ Fh,
                             float* __restrict__ Xh, float* __restrict__ Fw) {
  int i = blockIdx.x * 256 + threadIdx.x;
  Xh[2 * SLOT + i] = Fh[i];
  Fw[2 * SLOT + i] = Fh[SLOT + i];
}

// ---------------- bf16 MFMA GEMM, 2-phase double-buffered LDS --------------
// C = tanh(A @ W^T + bias). Per K-step: STAGE(next buf) issued first (loads
// overlap compute), then compute(cur), then ONE __syncthreads (its implicit
// vmcnt(0) drain lands after the loads had the compute phase to complete).
// Accumulation order per output identical to the 2-barrier version.
template <int BM, int BN, int K, bool OUT_BF16>
__global__ __launch_bounds__(256) void gemm_mfma(
    const __hip_bfloat16* __restrict__ A, const __hip_bfloat16* __restrict__ W,
    const float* __restrict__ bias, float* __restrict__ Cf,
    __hip_bfloat16* __restrict__ Cb, int N) {
  __shared__ __align__(16) u16 lds[2][(BM + BN) * 64];
  const int tid = threadIdx.x;
  const int lane = tid & 63;
  const int wid = tid >> 6;
  const int wy = wid >> 1, wx = wid & 1;
  constexpr int WM = BM / 2, WN = BN / 2;
  constexpr int MB = WM / 16, NB = WN / 16;
  constexpr int NK = K / 64;
  const int bm = blockIdx.x * BM;
  const int bn = blockIdx.y * BN;
  const int rlo = lane & 15, quad = lane >> 4;

  f32x4 acc[MB][NB] = {};

  auto stage = [&](u16* base, int k0) {
    u16* As = base;
    u16* Ws = base + BM * 64;
    for (int c = tid; c < BM * 8; c += 256) {
      int r = c >> 3, o = (c & 7) ^ (r & 7);
      __builtin_amdgcn_global_load_lds(
          (const __attribute__((address_space(1))) void*)(A + (size_t)(bm + r) * K + k0 + o * 8),
          (__attribute__((address_space(3))) void*)(As + c * 8), 16, 0, 0);
    }
    for (int c = tid; c < BN * 8; c += 256) {
      int r = c >> 3, o = (c & 7) ^ (r & 7);
      __builtin_amdgcn_global_load_lds(
          (const __attribute__((address_space(1))) void*)(W + (size_t)(bn + r) * K + k0 + o * 8),
          (__attribute__((address_space(3))) void*)(Ws + c * 8), 16, 0, 0);
    }
  };
  auto compute = [&](const u16* base) {
    const u16* As = base;
    const u16* Ws = base + BM * 64;
#pragma unroll
    for (int kk = 0; kk < 2; kk++) {
      bf16x8 af[MB], bfr[NB];
#pragma unroll
      for (int mb = 0; mb < MB; mb++) {
        int r = wy * WM + mb * 16 + rlo;
        int o = (kk * 4 + quad) ^ (r & 7);
        af[mb] = *(const bf16x8*)(As + (r * 8 + o) * 8);
      }
#pragma unroll
      for (int nb = 0; nb < NB; nb++) {
        int r = wx * WN + nb * 16 + rlo;
        int o = (kk * 4 + quad) ^ (r & 7);
        bfr[nb] = *(const bf16x8*)(Ws + (r * 8 + o) * 8);
      }
#pragma unroll
      for (int mb = 0; mb < MB; mb++)
#pragma unroll
        for (int nb = 0; nb < NB; nb++)
          acc[mb][nb] = __builtin_amdgcn_mfma_f32_16x16x32_bf16(
              af[mb], bfr[nb], acc[mb][nb], 0, 0, 0);
    }
  };

  stage(&lds[0][0], 0);
  __syncthreads();
#pragma unroll 2
  for (int step = 0; step < NK; step++) {
    u16* cur = (step & 1) ? &lds[1][0] : &lds[0][0];
    u16* nxt = (step & 1) ? &lds[0][0] : &lds[1][0];
    if (step + 1 < NK) stage(nxt, (step + 1) * 64);
    compute(cur);
    if (step + 1 < NK) __syncthreads();
  }

#pragma unroll
  for (int mb = 0; mb < MB; mb++) {
#pragma unroll
    for (int nb = 0; nb < NB; nb++) {
      int n = bn + wx * WN + nb * 16 + rlo;
      float bv = bias[n];
#pragma unroll
      for (int rg = 0; rg < 4; rg++) {
        int m = bm + wy * WM + mb * 16 + quad * 4 + rg;
        float val = tanhf(acc[mb][nb][rg] + bv);
        if constexpr (OUT_BF16) {
          Cb[(size_t)m * N + n] = __float2bfloat16(val);
        } else {
          Cf[(size_t)m * N + n] = val;
        }
      }
    }
  }
}

// ---------------- Anderson step v2.1 (wave per row, reg-resident, f32) -----
template <int MK>
__global__ __launch_bounds__(256) void anderson_step_kernel(
    const float* __restrict__ Xh, const float* __restrict__ Fh,
    float* __restrict__ Xw, __hip_bfloat16* __restrict__ zc, int t) {
  const int lane = threadIdx.x & 63;
  const int wid = threadIdx.x >> 6;
  const int b = blockIdx.x * 4 + wid;
  const int base = b * D_LAT + 4 * lane;

  f32x4 f[MK + 1], x[MK + 1];
#pragma unroll
  for (int i = 0; i <= MK; i++) {
    int sl = (t - 1 - i) % NRING;
    f[i] = *(const f32x4*)(Fh + (size_t)sl * SLOT + base);
    x[i] = *(const f32x4*)(Xh + (size_t)sl * SLOT + base);
  }

  const f32x4 r = f[0] - x[0];
  f32x4 dF[MK], dG[MK];
#pragma unroll
  for (int i = 0; i < MK; i++) {
    dF[i] = f[i] - f[i + 1];
    dG[i] = dF[i] - (x[i] - x[i + 1]);
  }

  constexpr int NV = MK * (MK + 1) / 2 + MK;
  float vals[NV];
  {
    int p = 0;
#pragma unroll
    for (int i = 0; i < MK; i++)
#pragma unroll
      for (int j = i; j < MK; j++) {
        f32x4 q = dG[i] * dG[j];
        vals[p++] = q[0] + q[1] + q[2] + q[3];
      }
#pragma unroll
    for (int i = 0; i < MK; i++) {
      f32x4 q = dG[i] * r;
      vals[p++] = q[0] + q[1] + q[2] + q[3];
    }
  }
#pragma unroll
  for (int off = 1; off <= 32; off <<= 1)
#pragma unroll
    for (int v = 0; v < NV; v++) vals[v] += __shfl_xor(vals[v], off, 64);

  float A[MK][MK], bv[MK], alpha[MK];
  {
    int p = 0;
#pragma unroll
    for (int i = 0; i < MK; i++)
#pragma unroll
      for (int j = i; j < MK; j++) {
        A[i][j] = vals[p];
        A[j][i] = vals[p];
        p++;
      }
#pragma unroll
    for (int i = 0; i < MK; i++) A[i][i] += 1e-4f;
#pragma unroll
    for (int i = 0; i < MK; i++) bv[i] = vals[p++];
  }

#pragma unroll
  for (int c = 0; c < MK; c++) {
    float inv = 1.0f / A[c][c];
#pragma unroll
    for (int rr = c + 1; rr < MK; rr++) {
      float fct = A[rr][c] * inv;
#pragma unroll
      for (int cc = c; cc < MK; cc++) A[rr][cc] -= fct * A[c][cc];
      bv[rr] -= fct * bv[c];
    }
  }
#pragma unroll
  for (int i = MK - 1; i >= 0; i--) {
    float s = bv[i];
#pragma unroll
    for (int j = i + 1; j < MK; j++) s -= A[i][j] * alpha[j];
    alpha[i] = s / A[i][i];
  }

  f32x4 xo = f[0];
#pragma unroll
  for (int i = 0; i < MK; i++) xo -= dF[i] * alpha[i];
  *(f32x4*)(Xw + base) = xo;
  if (zc != nullptr) {
    union { __hip_bfloat16 h[4]; unsigned long long u; } cv;
#pragma unroll
    for (int j = 0; j < 4; j++) cv.h[j] = __float2bfloat16(xo[j]);
    *(unsigned long long*)(zc + (size_t)b * KCAT + 4 * lane) = cv.u;
  }
}

// ---------------- host orchestration ---------------------------------------
static void eval_f(const __hip_bfloat16* zc, const __hip_bfloat16* W1b,
                   const __hip_bfloat16* W2b, const float* b1, const float* b2,
                   __hip_bfloat16* hb, float* Fout, hipStream_t stream) {
  gemm_mfma<64, 64, KCAT, true><<<dim3(B_ROWS / 64, D_HID / 64), 256, 0,
                                  stream>>>(zc, W1b, b1, nullptr, hb, D_HID);
  gemm_mfma<32, 32, D_HID, false><<<dim3(B_ROWS / 32, D_LAT / 32), 256, 0,
                                    stream>>>(hb, W2b, b2, Fout, nullptr,
                                              D_LAT);
}

extern "C" void kernel_launch(void* const* d_in, const int* in_sizes, int n_in,
                              void* d_out, int out_size, void* d_ws,
                              size_t ws_size, hipStream_t stream) {
  const float* ctx = (const float*)d_in[0];
  const float* W1 = (const float*)d_in[1];
  const float* b1 = (const float*)d_in[2];
  const float* W2 = (const float*)d_in[3];
  const float* b2 = (const float*)d_in[4];
  float* out = (float*)d_out;

  float* ws = (float*)d_ws;
  float* sig = ws;                       // 16
  float* vA = ws + 16;                   // 512
  float* vB = vA + KCAT;                 // 512
  float* uA = vB + KCAT;                 // 256
  float* uB = uA + D_LAT;                // 256
  float* G1p = uB + D_LAT;               // 512*512
  float* G2 = G1p + KCAT * KCAT;         // 256*256
  float* H1 = G2 + D_LAT * D_LAT;        // 512*512
  float* H2 = H1 + KCAT * KCAT;          // 256*256
  float* Xh = H2 + D_LAT * D_LAT;        // 7*SLOT
  float* Fh = Xh + NRING * SLOT;         // 7*SLOT
  __hip_bfloat16* W1b = (__hip_bfloat16*)(Fh + NRING * SLOT);  // 524288
  __hip_bfloat16* W2b = W1b + D_HID * KCAT;                    // 262144
  __hip_bfloat16* zc = W2b + D_LAT * D_HID;                    // 2048*512
  __hip_bfloat16* hb = zc + B_ROWS * KCAT;                     // 2048*1024
  // ~40 MB total

  init_kernel<<<(B_ROWS * KCAT + 255) / 256, 256, 0, stream>>>(ctx, zc, vA, uA,
                                                               G1p, G2);
  gram_kernel<<<1280, 256, 0, stream>>>(W1, W2, G1p, G2);
  colsum_kernel<<<64, 256, 0, stream>>>(W1, vA);
  gsq_kernel<<<160, 256, 0, stream>>>(G1p, G2, H1, H2);

  // power chain (12 launches):
  //  L1: G-step u only: u0(uA)->u1(uB)
  pmv_kernel<<<192, 256, 0, stream>>>(G1p, G2, vA, vB, uA, uB, 0.25f, 0);
  //  9 joint H-steps (each = 2 damped steps): v1->..->v19, u1->..->u19
  for (int j = 0; j < 9; j++) {
    const float *vi_, *ui_; float *vo_, *uo_;
    if ((j & 1) == 0) { vi_ = vA; vo_ = vB; ui_ = uB; uo_ = uA; }
    else              { vi_ = vB; vo_ = vA; ui_ = uA; uo_ = uB; }
    pmv_kernel<<<192, 256, 0, stream>>>(H1, H2, vi_, vo_, ui_, uo_, 0.0625f, 1);
  }
  //  exact G-steps: v19(vB)->v20(vA)->v21(vB); u19(uA)->u20(uB)->u21(uA)
  pmv_kernel<<<192, 256, 0, stream>>>(G1p, G2, vB, vA, uA, uB, 0.25f, 1);
  pmv_kernel<<<192, 256, 0, stream>>>(G1p, G2, vA, vB, uB, uA, 0.25f, 1);
  // sigma(v21, v20, u20, u21)
  sigma_kernel<<<1, 256, 0, stream>>>(vB, vA, uB, uA, sig);
  wfold_kernel<<<(D_HID * KCAT + D_LAT * D_HID + 255) / 256, 256, 0, stream>>>(
      W1, W2, sig, W1b, W2b);

  hipMemsetAsync(Xh, 0, SLOT * sizeof(float), stream);

  eval_f(zc, W1b, W2b, b1, b2, hb, Fh, stream);
  warm1_kernel<<<SLOT / 256, 256, 0, stream>>>(Fh, Xh, zc);
  eval_f(zc, W1b, W2b, b1, b2, hb, Fh + SLOT, stream);
  warm2_kernel<<<SLOT / 256, 256, 0, stream>>>(Fh, Xh, Fh);

  // Anderson loop: t = 3..25
  for (int t = 3; t <= 25; t++) {
    int mk = (t - 1 < 5) ? (t - 1) : 5;
    float* Xw = (t == 25) ? out : (Xh + (t % NRING) * SLOT);
    __hip_bfloat16* zarg = (t == 25) ? nullptr : zc;
    dim3 g(B_ROWS / 4);
    if (mk == 2)
      anderson_step_kernel<2><<<g, 256, 0, stream>>>(Xh, Fh, Xw, zarg, t);
    else if (mk == 3)
      anderson_step_kernel<3><<<g, 256, 0, stream>>>(Xh, Fh, Xw, zarg, t);
    else if (mk == 4)
      anderson_step_kernel<4><<<g, 256, 0, stream>>>(Xh, Fh, Xw, zarg, t);
    else
      anderson_step_kernel<5><<<g, 256, 0, stream>>>(Xh, Fh, Xw, zarg, t);
    if (t < 25) {
      eval_f(zc, W1b, W2b, b1, b2, hb, Fh + (t % NRING) * SLOT, stream);
    }
  }
}

// Round 9
// 768.794 us; speedup vs baseline: 1.2962x; 1.0602x over previous
//
#include <hip/hip_runtime.h>
#include <hip/hip_bf16.h>

// ---------------------------------------------------------------------------
// DEQ layer, MI355X round 13.
//  - REVERT operator squaring: gsq measured 60us (latency-bound, 160 blk,
//    16 serial stages) vs 36us saved -> net +25. Back to 21-launch pmv.
//  - KEEP 2-phase double-buffered GEMM (round-12's offsetting win, ~+30us).
//  - gram: float2 global staging loads (half the load instructions; LDS
//    rows are stride-66 so 8B alignment max -> float2 not float4).
//  - anderson v2.1 (f32, wave/row): at latency floor, unchanged.
// ---------------------------------------------------------------------------

#define B_ROWS 2048
#define D_LAT  256
#define D_CTX  256
#define D_HID  1024
#define KCAT   512
#define SLOT   (B_ROWS * D_LAT)
#define NRING  7

typedef __bf16 bf16x8 __attribute__((ext_vector_type(8)));
typedef float f32x4 __attribute__((ext_vector_type(4)));
typedef float f32x2 __attribute__((ext_vector_type(2)));
typedef unsigned short u16;

// ---------------- init: zc = [bf16(0)|bf16(ctx)], uA=1, vA=0, G=0 ----------
__global__ void init_kernel(const float* __restrict__ ctx,
                            __hip_bfloat16* __restrict__ zc,
                            float* __restrict__ vA, float* __restrict__ uA,
                            float* __restrict__ G1p, float* __restrict__ G2) {
  int i = blockIdx.x * 256 + threadIdx.x;
  if (i < B_ROWS * KCAT) {
    int b = i >> 9, c = i & 511;
    float v = (c < 256) ? 0.0f : ctx[b * 256 + (c - 256)];
    zc[i] = __float2bfloat16(v);
  }
  if (i < 512 * 512) G1p[i] = 0.0f;
  if (i < 256 * 256) G2[i] = 0.0f;
  if (i < KCAT) vA[i] = 0.0f;
  if (i < D_LAT) uA[i] = 1.0f;
}

// ---------------- Gram build, split-K x8, 64x32 tiles, atomic accum --------
// blocks 0..1023:  G1' = W1^T W1 (mode A)
// blocks 1024..1279: G2 = W2 W2^T (mode B)
// Staging vectorized to float2 global loads (LDS rows stride 66 -> 8B align).
__global__ __launch_bounds__(256) void gram_kernel(
    const float* __restrict__ W1, const float* __restrict__ W2,
    float* __restrict__ G1p, float* __restrict__ G2) {
  __shared__ float As[32][66];
  __shared__ float Bs[32][34];
  const int tid = threadIdx.x;
  const int tx = tid & 15, ty = tid >> 4;

  const float* X; float* G; int N, ti, tj, k0base; bool modeA;
  int b = blockIdx.x;
  if (b < 1024) {
    modeA = true; X = W1; G = G1p; N = 512;
    int s = b >> 7, t = b & 127;
    ti = t >> 4; tj = t & 15; k0base = s * 128;
  } else {
    modeA = false; b -= 1024; X = W2; G = G2; N = 256;
    int s = b >> 5, t = b & 31;
    ti = t >> 3; tj = t & 7; k0base = s * 128;
  }

  float acc[4][2] = {};
  for (int k0 = k0base; k0 < k0base + 128; k0 += 32) {
    if (modeA) {
      for (int idx = tid; idx < 1024; idx += 256) {
        int r2 = (idx & 31) * 2, c = idx >> 5;
        f32x2 v = *(const f32x2*)(X + (size_t)(k0 + c) * 512 + ti * 64 + r2);
        *(f32x2*)&As[c][r2] = v;
      }
      for (int idx = tid; idx < 512; idx += 256) {
        int r2 = (idx & 15) * 2, c = idx >> 4;
        f32x2 v = *(const f32x2*)(X + (size_t)(k0 + c) * 512 + tj * 32 + r2);
        *(f32x2*)&Bs[c][r2] = v;
      }
    } else {
      for (int idx = tid; idx < 1024; idx += 256) {
        int c2 = (idx & 15) * 2, r = idx >> 4;
        f32x2 v = *(const f32x2*)(X + (size_t)(ti * 64 + r) * 1024 + k0 + c2);
        As[c2][r] = v[0];
        As[c2 + 1][r] = v[1];
      }
      for (int idx = tid; idx < 512; idx += 256) {
        int c2 = (idx & 15) * 2, r = idx >> 4;
        f32x2 v = *(const f32x2*)(X + (size_t)(tj * 32 + r) * 1024 + k0 + c2);
        Bs[c2][r] = v[0];
        Bs[c2 + 1][r] = v[1];
      }
    }
    __syncthreads();
#pragma unroll
    for (int kk = 0; kk < 32; kk++) {
      const float2* ap = (const float2*)&As[kk][ty * 4];
      float2 a0 = ap[0], a1 = ap[1];
      float2 b0 = *(const float2*)&Bs[kk][tx * 2];
      float a[4] = {a0.x, a0.y, a1.x, a1.y};
      float bb[2] = {b0.x, b0.y};
#pragma unroll
      for (int i = 0; i < 4; i++)
#pragma unroll
        for (int j = 0; j < 2; j++) acc[i][j] += a[i] * bb[j];
    }
    __syncthreads();
  }
#pragma unroll
  for (int i = 0; i < 4; i++)
#pragma unroll
    for (int j = 0; j < 2; j++)
      atomicAdd(&G[(size_t)(ti * 64 + ty * 4 + i) * N + tj * 32 + tx * 2 + j],
                acc[i][j]);
}

// ---------------- colsum: vA += W1^T ones (atomic partials) ----------------
__global__ __launch_bounds__(256) void colsum_kernel(
    const float* __restrict__ W1, float* __restrict__ vA) {
  int b = blockIdx.x;
  for (int c = threadIdx.x; c < KCAT; c += 256) {
    float s = 0.f;
#pragma unroll
    for (int r = 0; r < 16; r++) s += W1[(size_t)(16 * b + r) * KCAT + c];
    atomicAdd(&vA[c], s);
  }
}

// ---------------- joint power matvec: out = 0.25 * G in --------------------
__global__ __launch_bounds__(256) void pmv_kernel(
    const float* __restrict__ G1p, const float* __restrict__ G2,
    const float* __restrict__ vi, float* __restrict__ vo,
    const float* __restrict__ ui, float* __restrict__ uo, int g1_active) {
  int gw = blockIdx.x * 4 + (threadIdx.x >> 6);
  int lane = threadIdx.x & 63;
  const float* G; const float* in; float* out; int n, r;
  if (gw < 512) {
    if (!g1_active) return;
    G = G1p; in = vi; out = vo; n = 512; r = gw;
  } else {
    G = G2; in = ui; out = uo; n = 256; r = gw - 512;
  }
  const float4* Gr = (const float4*)(G + (size_t)r * n);
  const float4* uv = (const float4*)in;
  float acc = 0.f;
  for (int c = lane; c < (n >> 2); c += 64) {
    float4 g = Gr[c], u = uv[c];
    acc += g.x * u.x + g.y * u.y + g.z * u.z + g.w * u.w;
  }
  for (int off = 32; off; off >>= 1) acc += __shfl_down(acc, off, 64);
  if (lane == 0) out[r] = 0.25f * acc;
}

// ---------------- sigma ----------------------------------------------------
// vA=v^21, vB=v^20, uA=u^20, uB=u^21 (0.25 damping compensated exactly).
__global__ __launch_bounds__(256) void sigma_kernel(
    const float* __restrict__ vA, const float* __restrict__ vB,
    const float* __restrict__ uA, const float* __restrict__ uB,
    float* __restrict__ sig) {
  float s[4] = {0.f, 0.f, 0.f, 0.f};
  for (int i = threadIdx.x; i < KCAT; i += 256) {
    s[0] += vA[i] * vB[i];
    s[1] += vA[i] * vA[i];
  }
  for (int i = threadIdx.x; i < D_LAT; i += 256) {
    s[2] += uA[i] * uA[i];
    s[3] += uA[i] * uB[i];
  }
  __shared__ float red[4][4];
  int lane = threadIdx.x & 63, w = threadIdx.x >> 6;
  for (int k = 0; k < 4; k++) {
    float a = s[k];
    for (int off = 32; off; off >>= 1) a += __shfl_down(a, off, 64);
    if (lane == 0) red[k][w] = a;
  }
  __syncthreads();
  if (threadIdx.x == 0) {
    float d0 = red[0][0] + red[0][1] + red[0][2] + red[0][3];
    float d1 = red[1][0] + red[1][1] + red[1][2] + red[1][3];
    float d2 = red[2][0] + red[2][1] + red[2][2] + red[2][3];
    float d3 = red[3][0] + red[3][1] + red[3][2] + red[3][3];
    sig[0] = sqrtf(0.25f * d0 / d1);
    sig[1] = sqrtf(0.25f * d2 / d3);
  }
}

// ---------------- fold sigma into bf16 weights -----------------------------
__global__ void wfold_kernel(const float* __restrict__ W1,
                             const float* __restrict__ W2,
                             const float* __restrict__ sig,
                             __hip_bfloat16* __restrict__ W1b,
                             __hip_bfloat16* __restrict__ W2b) {
  int i = blockIdx.x * 256 + threadIdx.x;
  if (i < D_HID * KCAT) W1b[i] = __float2bfloat16(W1[i] * sig[0]);
  int j = i - D_HID * KCAT;
  if (j >= 0 && j < D_LAT * D_HID) W2b[j] = __float2bfloat16(W2[j] * sig[1]);
}

// ---------------- warm-up fusions ------------------------------------------
__global__ void warm1_kernel(const float* __restrict__ Fh,
                             float* __restrict__ Xh,
                             __hip_bfloat16* __restrict__ zc) {
  int i = blockIdx.x * 256 + threadIdx.x;
  float v = Fh[i];
  Xh[SLOT + i] = v;
  zc[(i >> 8) * KCAT + (i & 255)] = __float2bfloat16(v);
}
__global__ void warm2_kernel(const float* __restrict__ Fh,
                             float* __restrict__ Xh, float* __restrict__ Fw) {
  int i = blockIdx.x * 256 + threadIdx.x;
  Xh[2 * SLOT + i] = Fh[i];
  Fw[2 * SLOT + i] = Fh[SLOT + i];
}

// ---------------- bf16 MFMA GEMM, 2-phase double-buffered LDS --------------
template <int BM, int BN, int K, bool OUT_BF16>
__global__ __launch_bounds__(256) void gemm_mfma(
    const __hip_bfloat16* __restrict__ A, const __hip_bfloat16* __restrict__ W,
    const float* __restrict__ bias, float* __restrict__ Cf,
    __hip_bfloat16* __restrict__ Cb, int N) {
  __shared__ __align__(16) u16 lds[2][(BM + BN) * 64];
  const int tid = threadIdx.x;
  const int lane = tid & 63;
  const int wid = tid >> 6;
  const int wy = wid >> 1, wx = wid & 1;
  constexpr int WM = BM / 2, WN = BN / 2;
  constexpr int MB = WM / 16, NB = WN / 16;
  constexpr int NK = K / 64;
  const int bm = blockIdx.x * BM;
  const int bn = blockIdx.y * BN;
  const int rlo = lane & 15, quad = lane >> 4;

  f32x4 acc[MB][NB] = {};

  auto stage = [&](u16* base, int k0) {
    u16* As = base;
    u16* Ws = base + BM * 64;
    for (int c = tid; c < BM * 8; c += 256) {
      int r = c >> 3, o = (c & 7) ^ (r & 7);
      __builtin_amdgcn_global_load_lds(
          (const __attribute__((address_space(1))) void*)(A + (size_t)(bm + r) * K + k0 + o * 8),
          (__attribute__((address_space(3))) void*)(As + c * 8), 16, 0, 0);
    }
    for (int c = tid; c < BN * 8; c += 256) {
      int r = c >> 3, o = (c & 7) ^ (r & 7);
      __builtin_amdgcn_global_load_lds(
          (const __attribute__((address_space(1))) void*)(W + (size_t)(bn + r) * K + k0 + o * 8),
          (__attribute__((address_space(3))) void*)(Ws + c * 8), 16, 0, 0);
    }
  };
  auto compute = [&](const u16* base) {
    const u16* As = base;
    const u16* Ws = base + BM * 64;
#pragma unroll
    for (int kk = 0; kk < 2; kk++) {
      bf16x8 af[MB], bfr[NB];
#pragma unroll
      for (int mb = 0; mb < MB; mb++) {
        int r = wy * WM + mb * 16 + rlo;
        int o = (kk * 4 + quad) ^ (r & 7);
        af[mb] = *(const bf16x8*)(As + (r * 8 + o) * 8);
      }
#pragma unroll
      for (int nb = 0; nb < NB; nb++) {
        int r = wx * WN + nb * 16 + rlo;
        int o = (kk * 4 + quad) ^ (r & 7);
        bfr[nb] = *(const bf16x8*)(Ws + (r * 8 + o) * 8);
      }
#pragma unroll
      for (int mb = 0; mb < MB; mb++)
#pragma unroll
        for (int nb = 0; nb < NB; nb++)
          acc[mb][nb] = __builtin_amdgcn_mfma_f32_16x16x32_bf16(
              af[mb], bfr[nb], acc[mb][nb], 0, 0, 0);
    }
  };

  stage(&lds[0][0], 0);
  __syncthreads();
#pragma unroll 2
  for (int step = 0; step < NK; step++) {
    u16* cur = (step & 1) ? &lds[1][0] : &lds[0][0];
    u16* nxt = (step & 1) ? &lds[0][0] : &lds[1][0];
    if (step + 1 < NK) stage(nxt, (step + 1) * 64);
    compute(cur);
    if (step + 1 < NK) __syncthreads();
  }

#pragma unroll
  for (int mb = 0; mb < MB; mb++) {
#pragma unroll
    for (int nb = 0; nb < NB; nb++) {
      int n = bn + wx * WN + nb * 16 + rlo;
      float bv = bias[n];
#pragma unroll
      for (int rg = 0; rg < 4; rg++) {
        int m = bm + wy * WM + mb * 16 + quad * 4 + rg;
        float val = tanhf(acc[mb][nb][rg] + bv);
        if constexpr (OUT_BF16) {
          Cb[(size_t)m * N + n] = __float2bfloat16(val);
        } else {
          Cf[(size_t)m * N + n] = val;
        }
      }
    }
  }
}

// ---------------- Anderson step v2.1 (wave per row, reg-resident, f32) -----
template <int MK>
__global__ __launch_bounds__(256) void anderson_step_kernel(
    const float* __restrict__ Xh, const float* __restrict__ Fh,
    float* __restrict__ Xw, __hip_bfloat16* __restrict__ zc, int t) {
  const int lane = threadIdx.x & 63;
  const int wid = threadIdx.x >> 6;
  const int b = blockIdx.x * 4 + wid;
  const int base = b * D_LAT + 4 * lane;

  f32x4 f[MK + 1], x[MK + 1];
#pragma unroll
  for (int i = 0; i <= MK; i++) {
    int sl = (t - 1 - i) % NRING;
    f[i] = *(const f32x4*)(Fh + (size_t)sl * SLOT + base);
    x[i] = *(const f32x4*)(Xh + (size_t)sl * SLOT + base);
  }

  const f32x4 r = f[0] - x[0];
  f32x4 dF[MK], dG[MK];
#pragma unroll
  for (int i = 0; i < MK; i++) {
    dF[i] = f[i] - f[i + 1];
    dG[i] = dF[i] - (x[i] - x[i + 1]);
  }

  constexpr int NV = MK * (MK + 1) / 2 + MK;
  float vals[NV];
  {
    int p = 0;
#pragma unroll
    for (int i = 0; i < MK; i++)
#pragma unroll
      for (int j = i; j < MK; j++) {
        f32x4 q = dG[i] * dG[j];
        vals[p++] = q[0] + q[1] + q[2] + q[3];
      }
#pragma unroll
    for (int i = 0; i < MK; i++) {
      f32x4 q = dG[i] * r;
      vals[p++] = q[0] + q[1] + q[2] + q[3];
    }
  }
#pragma unroll
  for (int off = 1; off <= 32; off <<= 1)
#pragma unroll
    for (int v = 0; v < NV; v++) vals[v] += __shfl_xor(vals[v], off, 64);

  float A[MK][MK], bv[MK], alpha[MK];
  {
    int p = 0;
#pragma unroll
    for (int i = 0; i < MK; i++)
#pragma unroll
      for (int j = i; j < MK; j++) {
        A[i][j] = vals[p];
        A[j][i] = vals[p];
        p++;
      }
#pragma unroll
    for (int i = 0; i < MK; i++) A[i][i] += 1e-4f;
#pragma unroll
    for (int i = 0; i < MK; i++) bv[i] = vals[p++];
  }

#pragma unroll
  for (int c = 0; c < MK; c++) {
    float inv = 1.0f / A[c][c];
#pragma unroll
    for (int rr = c + 1; rr < MK; rr++) {
      float fct = A[rr][c] * inv;
#pragma unroll
      for (int cc = c; cc < MK; cc++) A[rr][cc] -= fct * A[c][cc];
      bv[rr] -= fct * bv[c];
    }
  }
#pragma unroll
  for (int i = MK - 1; i >= 0; i--) {
    float s = bv[i];
#pragma unroll
    for (int j = i + 1; j < MK; j++) s -= A[i][j] * alpha[j];
    alpha[i] = s / A[i][i];
  }

  f32x4 xo = f[0];
#pragma unroll
  for (int i = 0; i < MK; i++) xo -= dF[i] * alpha[i];
  *(f32x4*)(Xw + base) = xo;
  if (zc != nullptr) {
    union { __hip_bfloat16 h[4]; unsigned long long u; } cv;
#pragma unroll
    for (int j = 0; j < 4; j++) cv.h[j] = __float2bfloat16(xo[j]);
    *(unsigned long long*)(zc + (size_t)b * KCAT + 4 * lane) = cv.u;
  }
}

// ---------------- host orchestration ---------------------------------------
static void eval_f(const __hip_bfloat16* zc, const __hip_bfloat16* W1b,
                   const __hip_bfloat16* W2b, const float* b1, const float* b2,
                   __hip_bfloat16* hb, float* Fout, hipStream_t stream) {
  gemm_mfma<64, 64, KCAT, true><<<dim3(B_ROWS / 64, D_HID / 64), 256, 0,
                                  stream>>>(zc, W1b, b1, nullptr, hb, D_HID);
  gemm_mfma<32, 32, D_HID, false><<<dim3(B_ROWS / 32, D_LAT / 32), 256, 0,
                                    stream>>>(hb, W2b, b2, Fout, nullptr,
                                              D_LAT);
}

extern "C" void kernel_launch(void* const* d_in, const int* in_sizes, int n_in,
                              void* d_out, int out_size, void* d_ws,
                              size_t ws_size, hipStream_t stream) {
  const float* ctx = (const float*)d_in[0];
  const float* W1 = (const float*)d_in[1];
  const float* b1 = (const float*)d_in[2];
  const float* W2 = (const float*)d_in[3];
  const float* b2 = (const float*)d_in[4];
  float* out = (float*)d_out;

  float* ws = (float*)d_ws;
  float* sig = ws;                       // 16
  float* vA = ws + 16;                   // 512
  float* vB = vA + KCAT;                 // 512
  float* uA = vB + KCAT;                 // 256
  float* uB = uA + D_LAT;                // 256
  float* G1p = uB + D_LAT;               // 512*512
  float* G2 = G1p + KCAT * KCAT;         // 256*256
  float* Xh = G2 + D_LAT * D_LAT;        // 7*SLOT
  float* Fh = Xh + NRING * SLOT;         // 7*SLOT
  __hip_bfloat16* W1b = (__hip_bfloat16*)(Fh + NRING * SLOT);  // 524288
  __hip_bfloat16* W2b = W1b + D_HID * KCAT;                    // 262144
  __hip_bfloat16* zc = W2b + D_LAT * D_HID;                    // 2048*512
  __hip_bfloat16* hb = zc + B_ROWS * KCAT;                     // 2048*1024
  // ~38.5 MB total

  init_kernel<<<(B_ROWS * KCAT + 255) / 256, 256, 0, stream>>>(ctx, zc, vA, uA,
                                                               G1p, G2);
  gram_kernel<<<1280, 256, 0, stream>>>(W1, W2, G1p, G2);
  colsum_kernel<<<64, 256, 0, stream>>>(W1, vA);

  // damped power chain: u-side its 1..21 (u0=ones->u21); v-side its 2..21
  for (int it = 1; it <= 21; it++) {
    const float* vi; float* vo;
    const float* ui; float* uo;
    if (it & 1) { vi = vB; vo = vA; ui = uA; uo = uB; }
    else        { vi = vA; vo = vB; ui = uB; uo = uA; }
    pmv_kernel<<<192, 256, 0, stream>>>(G1p, G2, vi, vo, ui, uo, it >= 2);
  }
  // final: vA=v21, vB=v20, uA=u20, uB=u21
  sigma_kernel<<<1, 256, 0, stream>>>(vA, vB, uA, uB, sig);
  wfold_kernel<<<(D_HID * KCAT + D_LAT * D_HID + 255) / 256, 256, 0, stream>>>(
      W1, W2, sig, W1b, W2b);

  hipMemsetAsync(Xh, 0, SLOT * sizeof(float), stream);

  eval_f(zc, W1b, W2b, b1, b2, hb, Fh, stream);
  warm1_kernel<<<SLOT / 256, 256, 0, stream>>>(Fh, Xh, zc);
  eval_f(zc, W1b, W2b, b1, b2, hb, Fh + SLOT, stream);
  warm2_kernel<<<SLOT / 256, 256, 0, stream>>>(Fh, Xh, Fh);

  // Anderson loop: t = 3..25
  for (int t = 3; t <= 25; t++) {
    int mk = (t - 1 < 5) ? (t - 1) : 5;
    float* Xw = (t == 25) ? out : (Xh + (t % NRING) * SLOT);
    __hip_bfloat16* zarg = (t == 25) ? nullptr : zc;
    dim3 g(B_ROWS / 4);
    if (mk == 2)
      anderson_step_kernel<2><<<g, 256, 0, stream>>>(Xh, Fh, Xw, zarg, t);
    else if (mk == 3)
      anderson_step_kernel<3><<<g, 256, 0, stream>>>(Xh, Fh, Xw, zarg, t);
    else if (mk == 4)
      anderson_step_kernel<4><<<g, 256, 0, stream>>>(Xh, Fh, Xw, zarg, t);
    else
      anderson_step_kernel<5><<<g, 256, 0, stream>>>(Xh, Fh, Xw, zarg, t);
    if (t < 25) {
      eval_f(zc, W1b, W2b, b1, b2, hb, Fh + (t % NRING) * SLOT, stream);
    }
  }
}